// Round 1
// baseline (779.438 us; speedup 1.0000x reference)
//
#include <hip/hip_runtime.h>
#include <stdint.h>

#define B_ 8
#define S_ 1024
#define D_ 2048
#define H_ 16
#define HD_ 128
#define NROW 8192      // B_*S_
#define NQKV 6144      // 3*D_

typedef __bf16 bf16;
typedef bf16  bf16x8 __attribute__((ext_vector_type(8)));
typedef bf16  bf16x4 __attribute__((ext_vector_type(4)));
typedef float f32x4  __attribute__((ext_vector_type(4)));

#define AS1 __attribute__((address_space(1)))
#define AS3 __attribute__((address_space(3)))

// async global->LDS, 16B per lane; LDS dest = wave-uniform base + lane*16
__device__ __forceinline__ void gl_lds16(const bf16* g, bf16* l) {
  __builtin_amdgcn_global_load_lds((AS1 void*)g, (AS3 void*)l, 16, 0, 0);
}

// ---------- fp32 -> bf16 (x4 vectorized) ----------
__global__ __launch_bounds__(256) void f2b4(const float* __restrict__ in,
                                            bf16* __restrict__ out, int n4) {
  int i = blockIdx.x * 256 + threadIdx.x;
  if (i >= n4) return;
  float4 v = reinterpret_cast<const float4*>(in)[i];
  bf16x4 o;
  o.x = (bf16)v.x; o.y = (bf16)v.y; o.z = (bf16)v.z; o.w = (bf16)v.w;
  reinterpret_cast<bf16x4*>(out)[i] = o;
}

// ---------- pack bq|bk|bv into one 6144 fp32 vector ----------
__global__ void packb(const float* __restrict__ a, const float* __restrict__ b,
                      const float* __restrict__ c, float* __restrict__ o) {
  int i = blockIdx.x * 256 + threadIdx.x;
  if (i >= NQKV) return;
  o[i] = (i < 2048) ? a[i] : (i < 4096 ? b[i - 2048] : c[i - 4096]);
}

// ---------- unified m97-style GEMM: C[M,N] = A[M,K] * B[N,K]^T (+bias)(+=C) --
// Row strides la/lb/lc; per-z-batch element strides za/zb/zc.
template <typename CT, bool BIAS, bool ACCUM>
__global__ __launch_bounds__(256) void gemm_bt(const bf16* __restrict__ A,
                                               const bf16* __restrict__ Bm,
                                               const float* __restrict__ bias,
                                               CT* __restrict__ C,
                                               int M, int N, int K,
                                               long la, long lb, long lc,
                                               long za, long zb, long zc) {
  __shared__ __align__(16) bf16 As[128 * 32];
  __shared__ __align__(16) bf16 Bs[128 * 32];
  const int z = blockIdx.z;
  A  += (long)z * za;
  Bm += (long)z * zb;
  C  += (long)z * zc;
  const int tid = threadIdx.x;
  const int w = tid >> 6, l = tid & 63;
  const int wm = (w & 1) * 64, wn = (w >> 1) * 64;
  const int m0 = blockIdx.y * 128, n0 = blockIdx.x * 128;
  const int lr = l & 15, lk = (l >> 4) * 8;
  const int er = (l >> 4) * 4;

  const bf16* ag = A  + (long)(m0 + (tid >> 2)) * la + (tid & 3) * 8;
  const bf16* bg = Bm + (long)(n0 + (tid >> 2)) * lb + (tid & 3) * 8;
  bf16* al = As + (w * 16) * 32;
  bf16* bl = Bs + (w * 16) * 32;

  f32x4 acc[4][4] = {};

  for (int k0 = 0; k0 < K; k0 += 32) {
    gl_lds16(ag + k0,            al);
    gl_lds16(ag + 64 * la + k0,  al + 64 * 32);
    gl_lds16(bg + k0,            bl);
    gl_lds16(bg + 64 * lb + k0,  bl + 64 * 32);
    __syncthreads();
    bf16x8 af[4], bfr[4];
#pragma unroll
    for (int mi = 0; mi < 4; mi++)
      af[mi] = *reinterpret_cast<const bf16x8*>(As + (wm + mi * 16 + lr) * 32 + lk);
#pragma unroll
    for (int ni = 0; ni < 4; ni++)
      bfr[ni] = *reinterpret_cast<const bf16x8*>(Bs + (wn + ni * 16 + lr) * 32 + lk);
#pragma unroll
    for (int mi = 0; mi < 4; mi++)
#pragma unroll
      for (int ni = 0; ni < 4; ni++)
        acc[mi][ni] = __builtin_amdgcn_mfma_f32_16x16x32_bf16(af[mi], bfr[ni], acc[mi][ni], 0, 0, 0);
    __syncthreads();
  }

#pragma unroll
  for (int mi = 0; mi < 4; mi++) {
#pragma unroll
    for (int ni = 0; ni < 4; ni++) {
      const int col = n0 + wn + ni * 16 + lr;
      float bv = 0.0f;
      if constexpr (BIAS) bv = bias[col];
      const long base = (long)(m0 + wm + mi * 16 + er) * lc + col;
#pragma unroll
      for (int r = 0; r < 4; r++) {
        float v = acc[mi][ni][r] + bv;
        if constexpr (ACCUM) v += (float)C[base + (long)r * lc];
        C[base + (long)r * lc] = (CT)v;
      }
    }
  }
}

// ---------- in-place RoPE on Q/K (first 64 dims of each head) ----------
__global__ __launch_bounds__(256) void rope_qk(bf16* __restrict__ QKV,
                                               const float* __restrict__ ch,
                                               const float* __restrict__ sh) {
  int idx = blockIdx.x * 256 + threadIdx.x;
  if (idx >= NROW * H_ * 2 * 32) return;
  int hd = idx & 31;
  int qk = (idx >> 5) & 1;
  int h  = (idx >> 6) & 15;
  int row = idx >> 10;             // 0..8191 = (b,s)
  int s = row & (S_ - 1);
  long base = (long)row * NQKV + qk * 2048 + h * HD_ + hd;
  float a  = (float)QKV[base];
  float b2 = (float)QKV[base + 32];
  float c = ch[s * 32 + hd], sn = sh[s * 32 + hd];
  QKV[base]      = (bf16)(a * c - b2 * sn);
  QKV[base + 32] = (bf16)(b2 * c + a * sn);
}

// ---------- K/V transpose: QKV K/V-region (b,s,h,hd) -> Xt[b,h,hd,t] --------
__global__ __launch_bounds__(256) void kvtrans(const bf16* __restrict__ QKV,
                                               bf16* __restrict__ Kt,
                                               bf16* __restrict__ Vt) {
  __shared__ unsigned short T[128 * 130];
  const int bid = blockIdx.x;          // kv*1024 + bh*8 + tb
  const int tb = bid & 7, bh = (bid >> 3) & 127, kv = bid >> 10;
  const int b = bh >> 4, h = bh & 15;
  const int tid = threadIdx.x;
  const bf16* src = QKV + (long)(b * S_ + tb * 128) * NQKV + 2048 + kv * 2048 + h * HD_;
#pragma unroll
  for (int it = 0; it < 8; it++) {
    int chunk = it * 256 + tid;
    int r = chunk >> 4, hc = (chunk & 15) * 8;
    bf16x8 v = *reinterpret_cast<const bf16x8*>(src + (long)r * NQKV + hc);
    union { bf16x8 v8; unsigned short u[8]; } u8; u8.v8 = v;
#pragma unroll
    for (int j = 0; j < 8; j++) T[r * 130 + hc + j] = u8.u[j];
  }
  __syncthreads();
  bf16* dst = (kv ? Vt : Kt) + (long)bh * HD_ * S_ + tb * 128;
#pragma unroll
  for (int it = 0; it < 8; it++) {
    int chunk = it * 256 + tid;
    int hd = chunk >> 4, tc = (chunk & 15) * 8;
    union { bf16x8 v8; unsigned short u[8]; } u8;
#pragma unroll
    for (int j = 0; j < 8; j++) u8.u[j] = T[(tc + j) * 130 + hd];
    *reinterpret_cast<bf16x8*>(dst + (long)hd * S_ + tc) = u8.v8;
  }
}

// ---------- Ob += Q * W2^T per (b,h):  M=1024(s) N=128(d) K=128(e) ----------
// W2[bh][d][e] = sum_t V[b,t,h,d] K[b,t,h,e]  (precomputed by gemm_bt batch)
__global__ __launch_bounds__(256) void qw2_gemm(const bf16* __restrict__ QKV,
                                                const bf16* __restrict__ W2,
                                                bf16* __restrict__ Ob) {
  __shared__ __align__(16) bf16 As[128 * 32];
  __shared__ __align__(16) bf16 Bs[128 * 32];
  const int z = blockIdx.z;            // bh
  const int b = z >> 4, h = z & 15;
  const int m0 = blockIdx.y * 128;
  const int tid = threadIdx.x;
  const int w = tid >> 6, l = tid & 63;
  const int wm = (w & 1) * 64, wn = (w >> 1) * 64;
  const int lr = l & 15, lk = (l >> 4) * 8;
  const int er = (l >> 4) * 4;

  const bf16* ag = QKV + (long)(b * S_ + m0 + (tid >> 2)) * NQKV + h * HD_ + (tid & 3) * 8;
  const bf16* bg = W2 + (long)z * (HD_ * HD_) + (tid >> 2) * HD_ + (tid & 3) * 8;
  bf16* al = As + (w * 16) * 32;
  bf16* bl = Bs + (w * 16) * 32;

  f32x4 acc[4][4] = {};

#pragma unroll
  for (int k0 = 0; k0 < HD_; k0 += 32) {
    gl_lds16(ag + k0,                   al);
    gl_lds16(ag + (long)64 * NQKV + k0, al + 64 * 32);
    gl_lds16(bg + k0,                   bl);
    gl_lds16(bg + 64 * HD_ + k0,        bl + 64 * 32);
    __syncthreads();
    bf16x8 af[4], bfr[4];
#pragma unroll
    for (int mi = 0; mi < 4; mi++)
      af[mi] = *reinterpret_cast<const bf16x8*>(As + (wm + mi * 16 + lr) * 32 + lk);
#pragma unroll
    for (int ni = 0; ni < 4; ni++)
      bfr[ni] = *reinterpret_cast<const bf16x8*>(Bs + (wn + ni * 16 + lr) * 32 + lk);
#pragma unroll
    for (int mi = 0; mi < 4; mi++)
#pragma unroll
      for (int ni = 0; ni < 4; ni++)
        acc[mi][ni] = __builtin_amdgcn_mfma_f32_16x16x32_bf16(af[mi], bfr[ni], acc[mi][ni], 0, 0, 0);
    __syncthreads();
  }

#pragma unroll
  for (int mi = 0; mi < 4; mi++) {
#pragma unroll
    for (int ni = 0; ni < 4; ni++) {
      const int col = h * HD_ + wn + ni * 16 + lr;
#pragma unroll
      for (int r = 0; r < 4; r++) {
        const int sl = m0 + wm + mi * 16 + er + r;
        const long idx = (long)(b * S_ + sl) * D_ + col;
        Ob[idx] = (bf16)((float)Ob[idx] + acc[mi][ni][r]);
      }
    }
  }
}

extern "C" void kernel_launch(void* const* d_in, const int* in_sizes, int n_in,
                              void* d_out, int out_size, void* d_ws, size_t ws_size,
                              hipStream_t stream) {
  const float* x   = (const float*)d_in[0];
  const float* wq  = (const float*)d_in[1];
  const float* bq  = (const float*)d_in[2];
  const float* wk  = (const float*)d_in[3];
  const float* bk  = (const float*)d_in[4];
  const float* wv  = (const float*)d_in[5];
  const float* bv  = (const float*)d_in[6];
  const float* wo  = (const float*)d_in[7];
  const float* bo  = (const float*)d_in[8];
  const float* ch  = (const float*)d_in[9];
  const float* sh  = (const float*)d_in[10];
  const float* mask = (const float*)d_in[11];
  float* out = (float*)d_out;

  // Workspace layout (~262 MiB; prior session proved ws_size >= 320 MiB):
  //   [0,96M)          QKV    (live: GEMM1 .. qw2)
  //   [96M,128M)       Vt     (live: kvtrans .. maskV)
  //   [128M,160M)      Kt     (live: kvtrans .. ktv)
  //   [160M,168M)      wob
  //   [168M,+24K)      bqkv
  //   [~168M,+2M)      maskb
  //   [~170M,+4M)      W2
  //   [~174M,+32M)     Ob
  //   [~206M,+32M)     xb     (dead after GEMM1)
  //   [~238M,+24M)     wqkvb  (dead after GEMM1)
  char* ws = (char*)d_ws;
  bf16*  QKV   = (bf16*)(ws);                    // 96 MB
  bf16*  Vt    = (bf16*)(ws + 100663296);        // 32 MB
  bf16*  Kt    = (bf16*)(ws + 134217728);        // 32 MB
  bf16*  wob   = (bf16*)(ws + 167772160);        // 8 MB
  float* bqkv  = (float*)(ws + 176160768);       // 24 KB
  bf16*  maskb = (bf16*)(ws + 176185344);        // 2 MB
  bf16*  W2    = (bf16*)(ws + 178282496);        // 4 MB
  bf16*  Ob    = (bf16*)(ws + 182476800);        // 32 MB
  bf16*  xb    = (bf16*)(ws + 216031232);        // 32 MB (dead after GEMM1)
  bf16*  wqkvb = (bf16*)(ws + 249585664);        // 24 MB (dead after GEMM1)

  f2b4<<<16384, 256, 0, stream>>>(x, xb, 4194304);
  f2b4<<<4096, 256, 0, stream>>>(wq, wqkvb,           1048576);
  f2b4<<<4096, 256, 0, stream>>>(wk, wqkvb + 4194304, 1048576);
  f2b4<<<4096, 256, 0, stream>>>(wv, wqkvb + 8388608, 1048576);
  f2b4<<<4096, 256, 0, stream>>>(wo, wob, 1048576);
  f2b4<<<1024, 256, 0, stream>>>(mask, maskb, 262144);
  packb<<<24, 256, 0, stream>>>(bq, bk, bv, bqkv);

  // QKV = x @ [wq;wk;wv]^T + bias  (8192 x 6144 x 2048)
  gemm_bt<bf16, true, false><<<dim3(48, 64, 1), 256, 0, stream>>>(
      xb, wqkvb, bqkv, QKV, NROW, NQKV, D_,
      (long)D_, (long)D_, (long)NQKV, 0L, 0L, 0L);

  rope_qk<<<32768, 256, 0, stream>>>(QKV, ch, sh);
  kvtrans<<<2048, 256, 0, stream>>>(QKV, Kt, Vt);

  // W2[bh][d][e] = sum_t V[t,d] K[t,e]   (128 batches of 128x128xK=1024)
  gemm_bt<bf16, false, false><<<dim3(1, 1, 128), 256, 0, stream>>>(
      Vt, Kt, nullptr, W2, HD_, HD_, S_,
      (long)S_, (long)S_, (long)HD_,
      (long)(HD_ * S_), (long)(HD_ * S_), (long)(HD_ * HD_));

  // Ob = mask @ V  per batch  (8 batches of 1024 x 2048 x K=1024)
  gemm_bt<bf16, false, false><<<dim3(16, 8, 8), 256, 0, stream>>>(
      maskb, Vt, nullptr, Ob, S_, D_, S_,
      (long)S_, (long)S_, (long)D_,
      0L, (long)(D_ * S_), (long)(S_ * D_));

  // Ob += Q @ W2^T  per (b,h)  (128 batches of 1024 x 128 x K=128)
  qw2_gemm<<<dim3(1, 8, 128), 256, 0, stream>>>(QKV, W2, Ob);

  // out = a_sum @ wo^T + bo  (8192 x 2048 x 2048, fp32 output)
  gemm_bt<float, true, false><<<dim3(16, 64, 1), 256, 0, stream>>>(
      Ob, wob, bo, out, NROW, D_, D_,
      (long)D_, (long)D_, (long)D_, 0L, 0L, 0L);
}

// Round 2
// 642.768 us; speedup vs baseline: 1.2126x; 1.2126x over previous
//
#include <hip/hip_runtime.h>
#include <stdint.h>

#define B_ 8
#define S_ 1024
#define D_ 2048
#define H_ 16
#define HD_ 128
#define NROW 8192      // B_*S_
#define NQKV 6144      // 3*D_

typedef __bf16 bf16;
typedef bf16  bf16x8 __attribute__((ext_vector_type(8)));
typedef bf16  bf16x4 __attribute__((ext_vector_type(4)));
typedef float f32x4  __attribute__((ext_vector_type(4)));

#define AS1 __attribute__((address_space(1)))
#define AS3 __attribute__((address_space(3)))

// async global->LDS, 16B per lane; LDS dest = wave-uniform base + lane*16
__device__ __forceinline__ void gl_lds16(const bf16* g, bf16* l) {
  __builtin_amdgcn_global_load_lds((AS1 void*)g, (AS3 void*)l, 16, 0, 0);
}

// ---------- fp32 -> bf16 (x4 vectorized) ----------
__global__ __launch_bounds__(256) void f2b4(const float* __restrict__ in,
                                            bf16* __restrict__ out, int n4) {
  int i = blockIdx.x * 256 + threadIdx.x;
  if (i >= n4) return;
  float4 v = reinterpret_cast<const float4*>(in)[i];
  bf16x4 o;
  o.x = (bf16)v.x; o.y = (bf16)v.y; o.z = (bf16)v.z; o.w = (bf16)v.w;
  reinterpret_cast<bf16x4*>(out)[i] = o;
}

// ---------- pack bq|bk|bv into one 6144 fp32 vector ----------
__global__ void packb(const float* __restrict__ a, const float* __restrict__ b,
                      const float* __restrict__ c, float* __restrict__ o) {
  int i = blockIdx.x * 256 + threadIdx.x;
  if (i >= NQKV) return;
  o[i] = (i < 2048) ? a[i] : (i < 4096 ? b[i - 2048] : c[i - 4096]);
}

// =====================================================================
// 256x256 8-phase GEMM (m201-style): C[M,N] = A[M,K] * B[N,K]^T (+bias)
// 512 threads = 8 waves (2M x 4N), BK=64, 128KiB dbuf LDS, st_16x32 swizzle.
// LDS per tile: subtile(s,sk) = 16rows x 32cols bf16 contiguous (1024B) at
// elem (s*2+sk)*512; within subtile elem(r,c) at r*32 + (c ^ ((r&8)<<1)).
// Staged by gl_lds (1 wave-call = 1 subtile) from inverse-swizzled global src.
// =====================================================================
#define READ_A(QA, Ab)                                                        \
  _Pragma("unroll") for (int mi = 0; mi < 4; mi++)                            \
  _Pragma("unroll") for (int ks = 0; ks < 2; ks++)                            \
    af[mi][ks] = *reinterpret_cast<const bf16x8*>(                            \
        (Ab) + aoff + (((QA)*4 + mi)*2 + ks)*512);

#define READ_B(QB, Bb, BFR)                                                   \
  _Pragma("unroll") for (int ni = 0; ni < 2; ni++)                            \
  _Pragma("unroll") for (int ks = 0; ks < 2; ks++)                            \
    BFR[ni][ks] = *reinterpret_cast<const bf16x8*>(                           \
        (Bb) + boff + (((QB)*2 + ni)*2 + ks)*512);

#define MFMA_Q(QA, QB, BFR)                                                   \
  _Pragma("unroll") for (int mi = 0; mi < 4; mi++)                            \
  _Pragma("unroll") for (int ni = 0; ni < 2; ni++)                            \
  _Pragma("unroll") for (int ks = 0; ks < 2; ks++)                            \
    acc[(QA)*4 + mi][(QB)*2 + ni] = __builtin_amdgcn_mfma_f32_16x16x32_bf16(  \
        af[mi][ks], BFR[ni][ks], acc[(QA)*4 + mi][(QB)*2 + ni], 0, 0, 0);

#define STAGE_A(dst, koff)                                                    \
  gl_lds16(agA + (koff),                (dst) + wid*1024);                    \
  gl_lds16(agA + (koff) + 32,           (dst) + wid*1024 + 512);              \
  gl_lds16(agA + 128*la + (koff),       (dst) + (wid + 8)*1024);              \
  gl_lds16(agA + 128*la + (koff) + 32,  (dst) + (wid + 8)*1024 + 512);

#define STAGE_B(dst, koff)                                                    \
  gl_lds16(agB + (koff),                (dst) + wid*1024);                    \
  gl_lds16(agB + (koff) + 32,           (dst) + wid*1024 + 512);              \
  gl_lds16(agB + 128*lb + (koff),       (dst) + (wid + 8)*1024);              \
  gl_lds16(agB + 128*lb + (koff) + 32,  (dst) + (wid + 8)*1024 + 512);

template <typename CT, bool BIAS, bool ACCUM>
__global__ __launch_bounds__(512, 2) void gemm256(const bf16* __restrict__ A,
                                                  const bf16* __restrict__ Bm,
                                                  const float* __restrict__ bias,
                                                  CT* __restrict__ C,
                                                  int M, int N, int K,
                                                  long la, long lb, long lc,
                                                  long za, long zb, long zc) {
  extern __shared__ __align__(16) bf16 lds[];   // 65536 elems = 128 KiB
  const int z = blockIdx.z;
  A  += (long)z * za;
  Bm += (long)z * zb;
  C  += (long)z * zc;
  const int tid  = threadIdx.x;
  const int wid  = tid >> 6;
  const int lane = tid & 63;
  const int wm0 = (wid >> 2) * 128;     // wave row origin in 256-tile
  const int wn0 = (wid & 3) * 64;       // wave col origin
  const int m0 = blockIdx.y * 256, n0 = blockIdx.x * 256;

  // staging: lane -> (row rr, inverse-swizzled col cc) within a subtile
  const int rr = lane >> 2;
  const int cc = ((lane & 3) * 8) ^ ((rr & 8) << 1);
  const bf16* agA = A  + (long)(m0 + wid * 16 + rr) * la + cc;
  const bf16* agB = Bm + (long)(n0 + wid * 16 + rr) * lb + cc;

  // read-side per-lane base offsets (elems) incl. swizzle
  const int swz  = ((lane >> 4) * 8) ^ ((lane & 8) << 1);
  const int aoff = (wm0 >> 4) * 1024 + (lane & 15) * 32 + swz;
  const int boff = (wn0 >> 4) * 1024 + (lane & 15) * 32 + swz;

  f32x4 acc[8][4] = {};
  bf16x8 af[4][2], b0[2][2], b1[2][2];
  const int NT = K >> 6;

  // prologue: stage tile 0 into buf0, full drain
  { bf16* An = lds; bf16* Bn = lds + 16384;
    STAGE_A(An, 0); STAGE_B(Bn, 0); }
  asm volatile("s_waitcnt vmcnt(0)" ::: "memory");
  __builtin_amdgcn_s_barrier();

  for (int t = 0; t < NT; ++t) {
    const bf16* Ab = lds + (t & 1) * 32768;
    const bf16* Bb = Ab + 16384;
    bf16* An = lds + ((t & 1) ^ 1) * 32768;
    bf16* Bn = An + 16384;
    const long kn = (long)(t + 1) * 64;
    const bool pf = (t + 1) < NT;

    // ---- phase 1: quadrant (0,0); reads A-q0 (8) + B-q0 (4); stage A halves
    READ_A(0, Ab); READ_B(0, Bb, b0);
    if (pf) { STAGE_A(An, kn); }
    __builtin_amdgcn_s_barrier();
    asm volatile("s_waitcnt lgkmcnt(0)" ::: "memory");
    __builtin_amdgcn_sched_barrier(0);
    __builtin_amdgcn_s_setprio(1); MFMA_Q(0, 0, b0); __builtin_amdgcn_s_setprio(0);
    __builtin_amdgcn_s_barrier();

    // ---- phase 2: quadrant (0,1); reads B-q1 (4); stage B halves
    READ_B(1, Bb, b1);
    if (pf) { STAGE_B(Bn, kn); }
    __builtin_amdgcn_s_barrier();
    asm volatile("s_waitcnt lgkmcnt(0)" ::: "memory");
    __builtin_amdgcn_sched_barrier(0);
    __builtin_amdgcn_s_setprio(1); MFMA_Q(0, 1, b1); __builtin_amdgcn_s_setprio(0);
    __builtin_amdgcn_s_barrier();

    // ---- phase 3: quadrant (1,0); reads A-q1 (8)
    READ_A(1, Ab);
    __builtin_amdgcn_s_barrier();
    asm volatile("s_waitcnt lgkmcnt(0)" ::: "memory");
    __builtin_amdgcn_sched_barrier(0);
    __builtin_amdgcn_s_setprio(1); MFMA_Q(1, 0, b0); __builtin_amdgcn_s_setprio(0);
    __builtin_amdgcn_s_barrier();

    // ---- phase 4: quadrant (1,1); no reads; drain staged loads, tile barrier
    __builtin_amdgcn_s_setprio(1); MFMA_Q(1, 1, b1); __builtin_amdgcn_s_setprio(0);
    asm volatile("s_waitcnt vmcnt(0)" ::: "memory");
    __builtin_amdgcn_s_barrier();
  }

#pragma unroll
  for (int mi = 0; mi < 8; mi++) {
#pragma unroll
    for (int ni = 0; ni < 4; ni++) {
      const int col = n0 + wn0 + ni * 16 + (lane & 15);
      float bv = 0.0f;
      if constexpr (BIAS) bv = bias[col];
      const long base = (long)(m0 + wm0 + mi * 16 + (lane >> 4) * 4) * lc + col;
#pragma unroll
      for (int r = 0; r < 4; r++) {
        float v = acc[mi][ni][r] + bv;
        if constexpr (ACCUM) v += (float)C[base + (long)r * lc];
        C[base + (long)r * lc] = (CT)v;
      }
    }
  }
}

// ---------- m97-style 128^2 GEMM (kept for small shapes: W2) ----------
template <typename CT, bool BIAS, bool ACCUM>
__global__ __launch_bounds__(256) void gemm_bt(const bf16* __restrict__ A,
                                               const bf16* __restrict__ Bm,
                                               const float* __restrict__ bias,
                                               CT* __restrict__ C,
                                               int M, int N, int K,
                                               long la, long lb, long lc,
                                               long za, long zb, long zc) {
  __shared__ __align__(16) bf16 As[128 * 32];
  __shared__ __align__(16) bf16 Bs[128 * 32];
  const int z = blockIdx.z;
  A  += (long)z * za;
  Bm += (long)z * zb;
  C  += (long)z * zc;
  const int tid = threadIdx.x;
  const int w = tid >> 6, l = tid & 63;
  const int wm = (w & 1) * 64, wn = (w >> 1) * 64;
  const int m0 = blockIdx.y * 128, n0 = blockIdx.x * 128;
  const int lr = l & 15, lk = (l >> 4) * 8;
  const int er = (l >> 4) * 4;

  const bf16* ag = A  + (long)(m0 + (tid >> 2)) * la + (tid & 3) * 8;
  const bf16* bg = Bm + (long)(n0 + (tid >> 2)) * lb + (tid & 3) * 8;
  bf16* al = As + (w * 16) * 32;
  bf16* bl = Bs + (w * 16) * 32;

  f32x4 acc[4][4] = {};

  for (int k0 = 0; k0 < K; k0 += 32) {
    gl_lds16(ag + k0,            al);
    gl_lds16(ag + 64 * la + k0,  al + 64 * 32);
    gl_lds16(bg + k0,            bl);
    gl_lds16(bg + 64 * lb + k0,  bl + 64 * 32);
    __syncthreads();
    bf16x8 afr[4], bfr[4];
#pragma unroll
    for (int mi = 0; mi < 4; mi++)
      afr[mi] = *reinterpret_cast<const bf16x8*>(As + (wm + mi * 16 + lr) * 32 + lk);
#pragma unroll
    for (int ni = 0; ni < 4; ni++)
      bfr[ni] = *reinterpret_cast<const bf16x8*>(Bs + (wn + ni * 16 + lr) * 32 + lk);
#pragma unroll
    for (int mi = 0; mi < 4; mi++)
#pragma unroll
      for (int ni = 0; ni < 4; ni++)
        acc[mi][ni] = __builtin_amdgcn_mfma_f32_16x16x32_bf16(afr[mi], bfr[ni], acc[mi][ni], 0, 0, 0);
    __syncthreads();
  }

#pragma unroll
  for (int mi = 0; mi < 4; mi++) {
#pragma unroll
    for (int ni = 0; ni < 4; ni++) {
      const int col = n0 + wn + ni * 16 + lr;
      float bv = 0.0f;
      if constexpr (BIAS) bv = bias[col];
      const long base = (long)(m0 + wm + mi * 16 + er) * lc + col;
#pragma unroll
      for (int r = 0; r < 4; r++) {
        float v = acc[mi][ni][r] + bv;
        if constexpr (ACCUM) v += (float)C[base + (long)r * lc];
        C[base + (long)r * lc] = (CT)v;
      }
    }
  }
}

// ---------- in-place RoPE on Q/K (first 64 dims of each head) ----------
__global__ __launch_bounds__(256) void rope_qk(bf16* __restrict__ QKV,
                                               const float* __restrict__ ch,
                                               const float* __restrict__ sh) {
  int idx = blockIdx.x * 256 + threadIdx.x;
  if (idx >= NROW * H_ * 2 * 32) return;
  int hd = idx & 31;
  int qk = (idx >> 5) & 1;
  int h  = (idx >> 6) & 15;
  int row = idx >> 10;             // 0..8191 = (b,s)
  int s = row & (S_ - 1);
  long base = (long)row * NQKV + qk * 2048 + h * HD_ + hd;
  float a  = (float)QKV[base];
  float b2 = (float)QKV[base + 32];
  float c = ch[s * 32 + hd], sn = sh[s * 32 + hd];
  QKV[base]      = (bf16)(a * c - b2 * sn);
  QKV[base + 32] = (bf16)(b2 * c + a * sn);
}

// ---------- K/V transpose: QKV K/V-region (b,s,h,hd) -> Xt[b,h,hd,t] --------
__global__ __launch_bounds__(256) void kvtrans(const bf16* __restrict__ QKV,
                                               bf16* __restrict__ Kt,
                                               bf16* __restrict__ Vt) {
  __shared__ unsigned short T[128 * 130];
  const int bid = blockIdx.x;          // kv*1024 + bh*8 + tb
  const int tb = bid & 7, bh = (bid >> 3) & 127, kv = bid >> 10;
  const int b = bh >> 4, h = bh & 15;
  const int tid = threadIdx.x;
  const bf16* src = QKV + (long)(b * S_ + tb * 128) * NQKV + 2048 + kv * 2048 + h * HD_;
#pragma unroll
  for (int it = 0; it < 8; it++) {
    int chunk = it * 256 + tid;
    int r = chunk >> 4, hc = (chunk & 15) * 8;
    bf16x8 v = *reinterpret_cast<const bf16x8*>(src + (long)r * NQKV + hc);
    union { bf16x8 v8; unsigned short u[8]; } u8; u8.v8 = v;
#pragma unroll
    for (int j = 0; j < 8; j++) T[r * 130 + hc + j] = u8.u[j];
  }
  __syncthreads();
  bf16* dst = (kv ? Vt : Kt) + (long)bh * HD_ * S_ + tb * 128;
#pragma unroll
  for (int it = 0; it < 8; it++) {
    int chunk = it * 256 + tid;
    int hd = chunk >> 4, tc = (chunk & 15) * 8;
    union { bf16x8 v8; unsigned short u[8]; } u8;
#pragma unroll
    for (int j = 0; j < 8; j++) u8.u[j] = T[(tc + j) * 130 + hd];
    *reinterpret_cast<bf16x8*>(dst + (long)hd * S_ + tc) = u8.v8;
  }
}

// ---------- Ob += Q * W2^T per (b,h):  M=1024(s) N=128(d) K=128(e) ----------
__global__ __launch_bounds__(256) void qw2_gemm(const bf16* __restrict__ QKV,
                                                const bf16* __restrict__ W2,
                                                bf16* __restrict__ Ob) {
  __shared__ __align__(16) bf16 As[128 * 32];
  __shared__ __align__(16) bf16 Bs[128 * 32];
  const int z = blockIdx.z;            // bh
  const int b = z >> 4, h = z & 15;
  const int m0 = blockIdx.y * 128;
  const int tid = threadIdx.x;
  const int w = tid >> 6, l = tid & 63;
  const int wm = (w & 1) * 64, wn = (w >> 1) * 64;
  const int lr = l & 15, lk = (l >> 4) * 8;
  const int er = (l >> 4) * 4;

  const bf16* ag = QKV + (long)(b * S_ + m0 + (tid >> 2)) * NQKV + h * HD_ + (tid & 3) * 8;
  const bf16* bg = W2 + (long)z * (HD_ * HD_) + (tid >> 2) * HD_ + (tid & 3) * 8;
  bf16* al = As + (w * 16) * 32;
  bf16* bl = Bs + (w * 16) * 32;

  f32x4 acc[4][4] = {};

#pragma unroll
  for (int k0 = 0; k0 < HD_; k0 += 32) {
    gl_lds16(ag + k0,                   al);
    gl_lds16(ag + (long)64 * NQKV + k0, al + 64 * 32);
    gl_lds16(bg + k0,                   bl);
    gl_lds16(bg + 64 * HD_ + k0,        bl + 64 * 32);
    __syncthreads();
    bf16x8 afr[4], bfr[4];
#pragma unroll
    for (int mi = 0; mi < 4; mi++)
      afr[mi] = *reinterpret_cast<const bf16x8*>(As + (wm + mi * 16 + lr) * 32 + lk);
#pragma unroll
    for (int ni = 0; ni < 4; ni++)
      bfr[ni] = *reinterpret_cast<const bf16x8*>(Bs + (wn + ni * 16 + lr) * 32 + lk);
#pragma unroll
    for (int mi = 0; mi < 4; mi++)
#pragma unroll
      for (int ni = 0; ni < 4; ni++)
        acc[mi][ni] = __builtin_amdgcn_mfma_f32_16x16x32_bf16(afr[mi], bfr[ni], acc[mi][ni], 0, 0, 0);
    __syncthreads();
  }

#pragma unroll
  for (int mi = 0; mi < 4; mi++) {
#pragma unroll
    for (int ni = 0; ni < 4; ni++) {
      const int col = h * HD_ + wn + ni * 16 + lr;
#pragma unroll
      for (int r = 0; r < 4; r++) {
        const int sl = m0 + wm + mi * 16 + er + r;
        const long idx = (long)(b * S_ + sl) * D_ + col;
        Ob[idx] = (bf16)((float)Ob[idx] + acc[mi][ni][r]);
      }
    }
  }
}

extern "C" void kernel_launch(void* const* d_in, const int* in_sizes, int n_in,
                              void* d_out, int out_size, void* d_ws, size_t ws_size,
                              hipStream_t stream) {
  const float* x   = (const float*)d_in[0];
  const float* wq  = (const float*)d_in[1];
  const float* bq  = (const float*)d_in[2];
  const float* wk  = (const float*)d_in[3];
  const float* bk  = (const float*)d_in[4];
  const float* wv  = (const float*)d_in[5];
  const float* bv  = (const float*)d_in[6];
  const float* wo  = (const float*)d_in[7];
  const float* bo  = (const float*)d_in[8];
  const float* ch  = (const float*)d_in[9];
  const float* sh  = (const float*)d_in[10];
  const float* mask = (const float*)d_in[11];
  float* out = (float*)d_out;

  // allow 128 KiB dynamic LDS for the 256^2 kernels
  hipFuncSetAttribute(reinterpret_cast<const void*>(&gemm256<bf16, true, false>),
                      hipFuncAttributeMaxDynamicSharedMemorySize, 131072);
  hipFuncSetAttribute(reinterpret_cast<const void*>(&gemm256<bf16, false, false>),
                      hipFuncAttributeMaxDynamicSharedMemorySize, 131072);
  hipFuncSetAttribute(reinterpret_cast<const void*>(&gemm256<float, true, false>),
                      hipFuncAttributeMaxDynamicSharedMemorySize, 131072);

  char* ws = (char*)d_ws;
  bf16*  QKV   = (bf16*)(ws);                    // 96 MB
  bf16*  Vt    = (bf16*)(ws + 100663296);        // 32 MB
  bf16*  Kt    = (bf16*)(ws + 134217728);        // 32 MB
  bf16*  wob   = (bf16*)(ws + 167772160);        // 8 MB
  float* bqkv  = (float*)(ws + 176160768);       // 24 KB
  bf16*  maskb = (bf16*)(ws + 176185344);        // 2 MB
  bf16*  W2    = (bf16*)(ws + 178282496);        // 4 MB
  bf16*  Ob    = (bf16*)(ws + 182476800);        // 32 MB
  bf16*  xb    = (bf16*)(ws + 216031232);        // 32 MB (dead after GEMM1)
  bf16*  wqkvb = (bf16*)(ws + 249585664);        // 24 MB (dead after GEMM1)

  f2b4<<<16384, 256, 0, stream>>>(x, xb, 4194304);
  f2b4<<<4096, 256, 0, stream>>>(wq, wqkvb,           1048576);
  f2b4<<<4096, 256, 0, stream>>>(wk, wqkvb + 4194304, 1048576);
  f2b4<<<4096, 256, 0, stream>>>(wv, wqkvb + 8388608, 1048576);
  f2b4<<<4096, 256, 0, stream>>>(wo, wob, 1048576);
  f2b4<<<1024, 256, 0, stream>>>(mask, maskb, 262144);
  packb<<<24, 256, 0, stream>>>(bq, bk, bv, bqkv);

  // QKV = x @ [wq;wk;wv]^T + bias  (8192 x 6144 x 2048)
  gemm256<bf16, true, false><<<dim3(24, 32, 1), 512, 131072, stream>>>(
      xb, wqkvb, bqkv, QKV, NROW, NQKV, D_,
      (long)D_, (long)D_, (long)NQKV, 0L, 0L, 0L);

  rope_qk<<<32768, 256, 0, stream>>>(QKV, ch, sh);
  kvtrans<<<2048, 256, 0, stream>>>(QKV, Kt, Vt);

  // W2[bh][d][e] = sum_t V[t,d] K[t,e]   (128 batches of 128x128xK=1024)
  gemm_bt<bf16, false, false><<<dim3(1, 1, 128), 256, 0, stream>>>(
      Vt, Kt, nullptr, W2, HD_, HD_, S_,
      (long)S_, (long)S_, (long)HD_,
      (long)(HD_ * S_), (long)(HD_ * S_), (long)(HD_ * HD_));

  // Ob = mask @ V  per batch  (8 batches of 1024 x 2048 x K=1024)
  gemm256<bf16, false, false><<<dim3(8, 4, 8), 512, 131072, stream>>>(
      maskb, Vt, nullptr, Ob, S_, D_, S_,
      (long)S_, (long)S_, (long)D_,
      0L, (long)(D_ * S_), (long)(S_ * D_));

  // Ob += Q @ W2^T  per (b,h)  (128 batches of 1024 x 128 x K=128)
  qw2_gemm<<<dim3(1, 8, 128), 256, 0, stream>>>(QKV, W2, Ob);

  // out = a_sum @ wo^T + bo  (8192 x 2048 x 2048, fp32 output)
  gemm256<float, true, false><<<dim3(8, 32, 1), 512, 131072, stream>>>(
      Ob, wob, bo, out, NROW, D_, D_,
      (long)D_, (long)D_, (long)D_, 0L, 0L, 0L);
}

// Round 4
// 632.864 us; speedup vs baseline: 1.2316x; 1.0157x over previous
//
#include <hip/hip_runtime.h>
#include <stdint.h>

#define B_ 8
#define S_ 1024
#define D_ 2048
#define H_ 16
#define HD_ 128
#define NROW 8192      // B_*S_
#define NQKV 6144      // 3*D_

typedef __bf16 bf16;
typedef bf16  bf16x8 __attribute__((ext_vector_type(8)));
typedef bf16  bf16x4 __attribute__((ext_vector_type(4)));
typedef float f32x4  __attribute__((ext_vector_type(4)));

#define AS1 __attribute__((address_space(1)))
#define AS3 __attribute__((address_space(3)))

// async global->LDS, 16B per lane; LDS dest = wave-uniform base + lane*16
__device__ __forceinline__ void gl_lds16(const bf16* g, bf16* l) {
  __builtin_amdgcn_global_load_lds((AS1 void*)g, (AS3 void*)l, 16, 0, 0);
}

// ---------- fp32 -> bf16 (x4 vectorized) ----------
__global__ __launch_bounds__(256) void f2b4(const float* __restrict__ in,
                                            bf16* __restrict__ out, int n4) {
  int i = blockIdx.x * 256 + threadIdx.x;
  if (i >= n4) return;
  float4 v = reinterpret_cast<const float4*>(in)[i];
  bf16x4 o;
  o.x = (bf16)v.x; o.y = (bf16)v.y; o.z = (bf16)v.z; o.w = (bf16)v.w;
  reinterpret_cast<bf16x4*>(out)[i] = o;
}

// ---------- pack bq|bk|bv into one 6144 fp32 vector ----------
__global__ void packb(const float* __restrict__ a, const float* __restrict__ b,
                      const float* __restrict__ c, float* __restrict__ o) {
  int i = blockIdx.x * 256 + threadIdx.x;
  if (i >= NQKV) return;
  o[i] = (i < 2048) ? a[i] : (i < 4096 ? b[i - 2048] : c[i - 4096]);
}

// =====================================================================
// 256x256 GEMM, counted-vmcnt 4-phase schedule: C = A[M,K] * B[N,K]^T
// 512 threads = 8 waves (2M x 4N), BK=64, 128KiB dbuf LDS, st_16x32 swizzle.
// Staging split by K-HALF so the needed-at-phase load sets are wave-uniform:
//   per wave issue order/tile: H0 = {A sub wid, A sub wid+8, B sub wid,
//   B sub wid+8} all kh=0 (4 loads), then H1 = same, kh=1 (4 loads).
// P1 waits vmcnt(4) (H0 ready, H1 may fly), P3 waits vmcnt(4) (H1 ready,
// next tile's H0 may fly). No vmcnt(0) in steady state; 2 barriers/tile.
// =====================================================================
#define READ_A4(QA, KS, Ab)                                                   \
  _Pragma("unroll") for (int mi = 0; mi < 4; mi++)                            \
    af[mi] = *reinterpret_cast<const bf16x8*>(                                \
        (Ab) + aoff + ((((QA)*4 + mi)*2) + (KS))*512);

#define READ_B4(KS, Bb)                                                       \
  _Pragma("unroll") for (int ni = 0; ni < 4; ni++)                            \
    bfr[ni] = *reinterpret_cast<const bf16x8*>(                               \
        (Bb) + boff + ((ni*2) + (KS))*512);

#define MFMA16(QA)                                                            \
  _Pragma("unroll") for (int mi = 0; mi < 4; mi++)                            \
  _Pragma("unroll") for (int ni = 0; ni < 4; ni++)                            \
    acc[(QA)*4 + mi][ni] = __builtin_amdgcn_mfma_f32_16x16x32_bf16(           \
        af[mi], bfr[ni], acc[(QA)*4 + mi][ni], 0, 0, 0);

#define STAGE_H0(An, Bn, koff)                                                \
  gl_lds16(agA + (koff),           (An) + wid*1024);                          \
  gl_lds16(agA + 128*la + (koff),  (An) + (wid + 8)*1024);                    \
  gl_lds16(agB + (koff),           (Bn) + wid*1024);                          \
  gl_lds16(agB + 128*lb + (koff),  (Bn) + (wid + 8)*1024);

#define STAGE_H1(An, Bn, koff)                                                \
  gl_lds16(agA + (koff) + 32,          (An) + wid*1024 + 512);                \
  gl_lds16(agA + 128*la + (koff) + 32, (An) + (wid + 8)*1024 + 512);          \
  gl_lds16(agB + (koff) + 32,          (Bn) + wid*1024 + 512);                \
  gl_lds16(agB + 128*lb + (koff) + 32, (Bn) + (wid + 8)*1024 + 512);

template <typename CT, bool BIAS, bool ACCUM>
__global__ __launch_bounds__(512, 2) void gemm256(const bf16* __restrict__ A,
                                                  const bf16* __restrict__ Bm,
                                                  const float* __restrict__ bias,
                                                  CT* __restrict__ C,
                                                  int M, int N, int K,
                                                  long la, long lb, long lc,
                                                  long za, long zb, long zc) {
  extern __shared__ __align__(16) bf16 lds[];   // 65536 elems = 128 KiB
  const int z = blockIdx.z;
  A  += (long)z * za;
  Bm += (long)z * zb;
  C  += (long)z * zc;
  const int tid  = threadIdx.x;
  const int wid  = tid >> 6;
  const int lane = tid & 63;
  const int wm0 = (wid >> 2) * 128;     // wave row origin in 256-tile
  const int wn0 = (wid & 3) * 64;       // wave col origin
  const int m0 = blockIdx.y * 256, n0 = blockIdx.x * 256;

  // staging: lane -> (row rr, inverse-swizzled col cc) within a subtile
  const int rr = lane >> 2;
  const int cc = ((lane & 3) * 8) ^ ((rr & 8) << 1);
  const bf16* agA = A  + (long)(m0 + wid * 16 + rr) * la + cc;
  const bf16* agB = Bm + (long)(n0 + wid * 16 + rr) * lb + cc;

  // read-side per-lane base offsets (elems) incl. swizzle
  const int swz  = ((lane >> 4) * 8) ^ ((lane & 8) << 1);
  const int aoff = (wm0 >> 4) * 1024 + (lane & 15) * 32 + swz;
  const int boff = (wn0 >> 4) * 1024 + (lane & 15) * 32 + swz;

  f32x4 acc[8][4] = {};
  const int NT = K >> 6;

  // prologue: stage tile 0 (H0 then H1 -- issue order matters for vmcnt)
  { bf16* An = lds; bf16* Bn = lds + 16384;
    STAGE_H0(An, Bn, 0); STAGE_H1(An, Bn, 0); }

  for (int t = 0; t < NT; ++t) {
    const bf16* Ab = lds + (t & 1) * 32768;
    const bf16* Bb = Ab + 16384;
    bf16* An = lds + ((t & 1) ^ 1) * 32768;
    bf16* Bn = An + 16384;
    const long kn = (long)(t + 1) * 64;
    const bool pf = (t + 1) < NT;
    bf16x8 af[4], bfr[4];

    // ---- P1: kh=0, rows wm0..+63; H0(t) ready, H1(t) may still fly
    asm volatile("s_waitcnt vmcnt(4)" ::: "memory");
    __builtin_amdgcn_s_barrier();
    READ_A4(0, 0, Ab); READ_B4(0, Bb);
    if (pf) { STAGE_H0(An, Bn, kn); }
    asm volatile("s_waitcnt lgkmcnt(0)" ::: "memory");
    __builtin_amdgcn_sched_barrier(0);
    __builtin_amdgcn_s_setprio(1); MFMA16(0); __builtin_amdgcn_s_setprio(0);

    // ---- P2: kh=0, rows wm0+64..+127 (data already synced at P1)
    READ_A4(1, 0, Ab);
    asm volatile("s_waitcnt lgkmcnt(0)" ::: "memory");
    __builtin_amdgcn_sched_barrier(0);
    __builtin_amdgcn_s_setprio(1); MFMA16(1); __builtin_amdgcn_s_setprio(0);

    // ---- P3: kh=1; H1(t) ready, H0(t+1) may still fly
    if (pf) asm volatile("s_waitcnt vmcnt(4)" ::: "memory");
    else    asm volatile("s_waitcnt vmcnt(0)" ::: "memory");
    __builtin_amdgcn_s_barrier();
    READ_A4(0, 1, Ab); READ_B4(1, Bb);
    if (pf) { STAGE_H1(An, Bn, kn); }
    asm volatile("s_waitcnt lgkmcnt(0)" ::: "memory");
    __builtin_amdgcn_sched_barrier(0);
    __builtin_amdgcn_s_setprio(1); MFMA16(0); __builtin_amdgcn_s_setprio(0);

    // ---- P4: kh=1, rows wm0+64..+127
    READ_A4(1, 1, Ab);
    asm volatile("s_waitcnt lgkmcnt(0)" ::: "memory");
    __builtin_amdgcn_sched_barrier(0);
    __builtin_amdgcn_s_setprio(1); MFMA16(1); __builtin_amdgcn_s_setprio(0);
  }

#pragma unroll
  for (int mi = 0; mi < 8; mi++) {
#pragma unroll
    for (int ni = 0; ni < 4; ni++) {
      const int col = n0 + wn0 + ni * 16 + (lane & 15);
      float bv = 0.0f;
      if constexpr (BIAS) bv = bias[col];
      const long base = (long)(m0 + wm0 + mi * 16 + (lane >> 4) * 4) * lc + col;
#pragma unroll
      for (int r = 0; r < 4; r++) {
        float v = acc[mi][ni][r] + bv;
        if constexpr (ACCUM) v += (float)C[base + (long)r * lc];
        C[base + (long)r * lc] = (CT)v;
      }
    }
  }
}

// ---------- m97-style 128^2 GEMM (kept for small shapes: W2) ----------
template <typename CT, bool BIAS, bool ACCUM>
__global__ __launch_bounds__(256) void gemm_bt(const bf16* __restrict__ A,
                                               const bf16* __restrict__ Bm,
                                               const float* __restrict__ bias,
                                               CT* __restrict__ C,
                                               int M, int N, int K,
                                               long la, long lb, long lc,
                                               long za, long zb, long zc) {
  __shared__ __align__(16) bf16 As[128 * 32];
  __shared__ __align__(16) bf16 Bs[128 * 32];
  const int z = blockIdx.z;
  A  += (long)z * za;
  Bm += (long)z * zb;
  C  += (long)z * zc;
  const int tid = threadIdx.x;
  const int w = tid >> 6, l = tid & 63;
  const int wm = (w & 1) * 64, wn = (w >> 1) * 64;
  const int m0 = blockIdx.y * 128, n0 = blockIdx.x * 128;
  const int lr = l & 15, lk = (l >> 4) * 8;
  const int er = (l >> 4) * 4;

  const bf16* ag = A  + (long)(m0 + (tid >> 2)) * la + (tid & 3) * 8;
  const bf16* bg = Bm + (long)(n0 + (tid >> 2)) * lb + (tid & 3) * 8;
  bf16* al = As + (w * 16) * 32;
  bf16* bl = Bs + (w * 16) * 32;

  f32x4 acc[4][4] = {};

  for (int k0 = 0; k0 < K; k0 += 32) {
    gl_lds16(ag + k0,            al);
    gl_lds16(ag + 64 * la + k0,  al + 64 * 32);
    gl_lds16(bg + k0,            bl);
    gl_lds16(bg + 64 * lb + k0,  bl + 64 * 32);
    __syncthreads();
    bf16x8 afr[4], bfr[4];
#pragma unroll
    for (int mi = 0; mi < 4; mi++)
      afr[mi] = *reinterpret_cast<const bf16x8*>(As + (wm + mi * 16 + lr) * 32 + lk);
#pragma unroll
    for (int ni = 0; ni < 4; ni++)
      bfr[ni] = *reinterpret_cast<const bf16x8*>(Bs + (wn + ni * 16 + lr) * 32 + lk);
#pragma unroll
    for (int mi = 0; mi < 4; mi++)
#pragma unroll
      for (int ni = 0; ni < 4; ni++)
        acc[mi][ni] = __builtin_amdgcn_mfma_f32_16x16x32_bf16(afr[mi], bfr[ni], acc[mi][ni], 0, 0, 0);
    __syncthreads();
  }

#pragma unroll
  for (int mi = 0; mi < 4; mi++) {
#pragma unroll
    for (int ni = 0; ni < 4; ni++) {
      const int col = n0 + wn + ni * 16 + lr;
      float bv = 0.0f;
      if constexpr (BIAS) bv = bias[col];
      const long base = (long)(m0 + wm + mi * 16 + er) * lc + col;
#pragma unroll
      for (int r = 0; r < 4; r++) {
        float v = acc[mi][ni][r] + bv;
        if constexpr (ACCUM) v += (float)C[base + (long)r * lc];
        C[base + (long)r * lc] = (CT)v;
      }
    }
  }
}

// ---------- in-place RoPE on Q/K (first 64 dims of each head) ----------
__global__ __launch_bounds__(256) void rope_qk(bf16* __restrict__ QKV,
                                               const float* __restrict__ ch,
                                               const float* __restrict__ sh) {
  int idx = blockIdx.x * 256 + threadIdx.x;
  if (idx >= NROW * H_ * 2 * 32) return;
  int hd = idx & 31;
  int qk = (idx >> 5) & 1;
  int h  = (idx >> 6) & 15;
  int row = idx >> 10;             // 0..8191 = (b,s)
  int s = row & (S_ - 1);
  long base = (long)row * NQKV + qk * 2048 + h * HD_ + hd;
  float a  = (float)QKV[base];
  float b2 = (float)QKV[base + 32];
  float c = ch[s * 32 + hd], sn = sh[s * 32 + hd];
  QKV[base]      = (bf16)(a * c - b2 * sn);
  QKV[base + 32] = (bf16)(b2 * c + a * sn);
}

// ---------- K/V transpose: QKV K/V-region (b,s,h,hd) -> Xt[b,h,hd,t] --------
__global__ __launch_bounds__(256) void kvtrans(const bf16* __restrict__ QKV,
                                               bf16* __restrict__ Kt,
                                               bf16* __restrict__ Vt) {
  __shared__ unsigned short T[128 * 130];
  const int bid = blockIdx.x;          // kv*1024 + bh*8 + tb
  const int tb = bid & 7, bh = (bid >> 3) & 127, kv = bid >> 10;
  const int b = bh >> 4, h = bh & 15;
  const int tid = threadIdx.x;
  const bf16* src = QKV + (long)(b * S_ + tb * 128) * NQKV + 2048 + kv * 2048 + h * HD_;
#pragma unroll
  for (int it = 0; it < 8; it++) {
    int chunk = it * 256 + tid;
    int r = chunk >> 4, hc = (chunk & 15) * 8;
    bf16x8 v = *reinterpret_cast<const bf16x8*>(src + (long)r * NQKV + hc);
    union { bf16x8 v8; unsigned short u[8]; } u8; u8.v8 = v;
#pragma unroll
    for (int j = 0; j < 8; j++) T[r * 130 + hc + j] = u8.u[j];
  }
  __syncthreads();
  bf16* dst = (kv ? Vt : Kt) + (long)bh * HD_ * S_ + tb * 128;
#pragma unroll
  for (int it = 0; it < 8; it++) {
    int chunk = it * 256 + tid;
    int hd = chunk >> 4, tc = (chunk & 15) * 8;
    union { bf16x8 v8; unsigned short u[8]; } u8;
#pragma unroll
    for (int j = 0; j < 8; j++) u8.u[j] = T[(tc + j) * 130 + hd];
    *reinterpret_cast<bf16x8*>(dst + (long)hd * S_ + tc) = u8.v8;
  }
}

// ---------- Ob += Q * W2^T per (b,h):  M=1024(s) N=128(d) K=128(e) ----------
__global__ __launch_bounds__(256) void qw2_gemm(const bf16* __restrict__ QKV,
                                                const bf16* __restrict__ W2,
                                                bf16* __restrict__ Ob) {
  __shared__ __align__(16) bf16 As[128 * 32];
  __shared__ __align__(16) bf16 Bs[128 * 32];
  const int z = blockIdx.z;            // bh
  const int b = z >> 4, h = z & 15;
  const int m0 = blockIdx.y * 128;
  const int tid = threadIdx.x;
  const int w = tid >> 6, l = tid & 63;
  const int wm = (w & 1) * 64, wn = (w >> 1) * 64;
  const int lr = l & 15, lk = (l >> 4) * 8;
  const int er = (l >> 4) * 4;

  const bf16* ag = QKV + (long)(b * S_ + m0 + (tid >> 2)) * NQKV + h * HD_ + (tid & 3) * 8;
  const bf16* bg = W2 + (long)z * (HD_ * HD_) + (tid >> 2) * HD_ + (tid & 3) * 8;
  bf16* al = As + (w * 16) * 32;
  bf16* bl = Bs + (w * 16) * 32;

  f32x4 acc[4][4] = {};

#pragma unroll
  for (int k0 = 0; k0 < HD_; k0 += 32) {
    gl_lds16(ag + k0,                   al);
    gl_lds16(ag + (long)64 * NQKV + k0, al + 64 * 32);
    gl_lds16(bg + k0,                   bl);
    gl_lds16(bg + 64 * HD_ + k0,        bl + 64 * 32);
    __syncthreads();
    bf16x8 afr[4], bfr[4];
#pragma unroll
    for (int mi = 0; mi < 4; mi++)
      afr[mi] = *reinterpret_cast<const bf16x8*>(As + (wm + mi * 16 + lr) * 32 + lk);
#pragma unroll
    for (int ni = 0; ni < 4; ni++)
      bfr[ni] = *reinterpret_cast<const bf16x8*>(Bs + (wn + ni * 16 + lr) * 32 + lk);
#pragma unroll
    for (int mi = 0; mi < 4; mi++)
#pragma unroll
      for (int ni = 0; ni < 4; ni++)
        acc[mi][ni] = __builtin_amdgcn_mfma_f32_16x16x32_bf16(afr[mi], bfr[ni], acc[mi][ni], 0, 0, 0);
    __syncthreads();
  }

#pragma unroll
  for (int mi = 0; mi < 4; mi++) {
#pragma unroll
    for (int ni = 0; ni < 4; ni++) {
      const int col = h * HD_ + wn + ni * 16 + lr;
#pragma unroll
      for (int r = 0; r < 4; r++) {
        const int sl = m0 + wm + mi * 16 + er + r;
        const long idx = (long)(b * S_ + sl) * D_ + col;
        Ob[idx] = (bf16)((float)Ob[idx] + acc[mi][ni][r]);
      }
    }
  }
}

extern "C" void kernel_launch(void* const* d_in, const int* in_sizes, int n_in,
                              void* d_out, int out_size, void* d_ws, size_t ws_size,
                              hipStream_t stream) {
  const float* x   = (const float*)d_in[0];
  const float* wq  = (const float*)d_in[1];
  const float* bq  = (const float*)d_in[2];
  const float* wk  = (const float*)d_in[3];
  const float* bk  = (const float*)d_in[4];
  const float* wv  = (const float*)d_in[5];
  const float* bv  = (const float*)d_in[6];
  const float* wo  = (const float*)d_in[7];
  const float* bo  = (const float*)d_in[8];
  const float* ch  = (const float*)d_in[9];
  const float* sh  = (const float*)d_in[10];
  const float* mask = (const float*)d_in[11];
  float* out = (float*)d_out;

  // allow 128 KiB dynamic LDS for the 256^2 kernels
  hipFuncSetAttribute(reinterpret_cast<const void*>(&gemm256<bf16, true, false>),
                      hipFuncAttributeMaxDynamicSharedMemorySize, 131072);
  hipFuncSetAttribute(reinterpret_cast<const void*>(&gemm256<bf16, false, false>),
                      hipFuncAttributeMaxDynamicSharedMemorySize, 131072);
  hipFuncSetAttribute(reinterpret_cast<const void*>(&gemm256<float, true, false>),
                      hipFuncAttributeMaxDynamicSharedMemorySize, 131072);

  char* ws = (char*)d_ws;
  bf16*  QKV   = (bf16*)(ws);                    // 96 MB
  bf16*  Vt    = (bf16*)(ws + 100663296);        // 32 MB
  bf16*  Kt    = (bf16*)(ws + 134217728);        // 32 MB
  bf16*  wob   = (bf16*)(ws + 167772160);        // 8 MB
  float* bqkv  = (float*)(ws + 176160768);       // 24 KB
  bf16*  maskb = (bf16*)(ws + 176185344);        // 2 MB
  bf16*  W2    = (bf16*)(ws + 178282496);        // 4 MB
  bf16*  Ob    = (bf16*)(ws + 182476800);        // 32 MB
  bf16*  xb    = (bf16*)(ws + 216031232);        // 32 MB (dead after GEMM1)
  bf16*  wqkvb = (bf16*)(ws + 249585664);        // 24 MB (dead after GEMM1)

  f2b4<<<16384, 256, 0, stream>>>(x, xb, 4194304);
  f2b4<<<4096, 256, 0, stream>>>(wq, wqkvb,           1048576);
  f2b4<<<4096, 256, 0, stream>>>(wk, wqkvb + 4194304, 1048576);
  f2b4<<<4096, 256, 0, stream>>>(wv, wqkvb + 8388608, 1048576);
  f2b4<<<4096, 256, 0, stream>>>(wo, wob, 1048576);
  f2b4<<<1024, 256, 0, stream>>>(mask, maskb, 262144);
  packb<<<24, 256, 0, stream>>>(bq, bk, bv, bqkv);

  // QKV = x @ [wq;wk;wv]^T + bias  (8192 x 6144 x 2048)
  gemm256<bf16, true, false><<<dim3(24, 32, 1), 512, 131072, stream>>>(
      xb, wqkvb, bqkv, QKV, NROW, NQKV, D_,
      (long)D_, (long)D_, (long)NQKV, 0L, 0L, 0L);

  rope_qk<<<32768, 256, 0, stream>>>(QKV, ch, sh);
  kvtrans<<<2048, 256, 0, stream>>>(QKV, Kt, Vt);

  // W2[bh][d][e] = sum_t V[t,d] K[t,e]   (128 batches of 128x128xK=1024)
  gemm_bt<bf16, false, false><<<dim3(1, 1, 128), 256, 0, stream>>>(
      Vt, Kt, nullptr, W2, HD_, HD_, S_,
      (long)S_, (long)S_, (long)HD_,
      (long)(HD_ * S_), (long)(HD_ * S_), (long)(HD_ * HD_));

  // Ob = mask @ V  per batch  (8 batches of 1024 x 2048 x K=1024)
  gemm256<bf16, false, false><<<dim3(8, 4, 8), 512, 131072, stream>>>(
      maskb, Vt, nullptr, Ob, S_, D_, S_,
      (long)S_, (long)S_, (long)D_,
      0L, (long)(D_ * S_), (long)(S_ * D_));

  // Ob += Q @ W2^T  per (b,h)  (128 batches of 1024 x 128 x K=128)
  qw2_gemm<<<dim3(1, 8, 128), 256, 0, stream>>>(QKV, W2, Ob);

  // out = a_sum @ wo^T + bo  (8192 x 2048 x 2048, fp32 output)
  gemm256<float, true, false><<<dim3(8, 32, 1), 512, 131072, stream>>>(
      Ob, wob, bo, out, NROW, D_, D_,
      (long)D_, (long)D_, (long)D_, 0L, 0L, 0L);
}

// Round 5
// 630.277 us; speedup vs baseline: 1.2367x; 1.0041x over previous
//
#include <hip/hip_runtime.h>
#include <stdint.h>

#define B_ 8
#define S_ 1024
#define D_ 2048
#define H_ 16
#define HD_ 128
#define NROW 8192      // B_*S_
#define NQKV 6144      // 3*D_

typedef __bf16 bf16;
typedef bf16  bf16x8 __attribute__((ext_vector_type(8)));
typedef bf16  bf16x4 __attribute__((ext_vector_type(4)));
typedef float f32x4  __attribute__((ext_vector_type(4)));

#define AS1 __attribute__((address_space(1)))
#define AS3 __attribute__((address_space(3)))

// async global->LDS, 16B per lane; LDS dest = wave-uniform base + lane*16
__device__ __forceinline__ void gl_lds16(const bf16* g, bf16* l) {
  __builtin_amdgcn_global_load_lds((AS1 void*)g, (AS3 void*)l, 16, 0, 0);
}

// ---------- fused input prep: all fp32->bf16 conversions + bias pack --------
// float4-unit segments:
//   [0,4194304)         x    -> xb
//   [4194304,5242880)   wq   -> wqkvb
//   [5242880,6291456)   wk   -> wqkvb+4M
//   [6291456,7340032)   wv   -> wqkvb+8M
//   [7340032,8388608)   wo   -> wob
//   [8388608,8650752)   mask -> maskb
//   [8650752,8652288)   bq|bk|bv -> bqkv (fp32 copy)
__global__ __launch_bounds__(256) void prep(const float* __restrict__ x,
                                            const float* __restrict__ wq,
                                            const float* __restrict__ wk,
                                            const float* __restrict__ wv,
                                            const float* __restrict__ wo,
                                            const float* __restrict__ mask,
                                            const float* __restrict__ bq,
                                            const float* __restrict__ bk,
                                            const float* __restrict__ bv,
                                            bf16* __restrict__ xb,
                                            bf16* __restrict__ wqkvb,
                                            bf16* __restrict__ wob,
                                            bf16* __restrict__ maskb,
                                            float* __restrict__ bqkv) {
  long i = (long)blockIdx.x * 256 + threadIdx.x;
  if (i < 8650752) {
    const float* src; bf16* dst; long j;
    if (i < 4194304)      { src = x;    dst = xb;              j = i; }
    else if (i < 5242880) { src = wq;   dst = wqkvb;           j = i - 4194304; }
    else if (i < 6291456) { src = wk;   dst = wqkvb + 4194304; j = i - 5242880; }
    else if (i < 7340032) { src = wv;   dst = wqkvb + 8388608; j = i - 6291456; }
    else if (i < 8388608) { src = wo;   dst = wob;             j = i - 7340032; }
    else                  { src = mask; dst = maskb;           j = i - 8388608; }
    float4 v = reinterpret_cast<const float4*>(src)[j];
    bf16x4 o;
    o.x = (bf16)v.x; o.y = (bf16)v.y; o.z = (bf16)v.z; o.w = (bf16)v.w;
    reinterpret_cast<bf16x4*>(dst)[j] = o;
  } else {
    long e = (i - 8650752) * 4;   // 0..6143, 4-aligned; segments 2048-aligned
    const float* s = (e < 2048) ? bq + e : (e < 4096 ? bk + (e - 2048) : bv + (e - 4096));
    *reinterpret_cast<float4*>(bqkv + e) = *reinterpret_cast<const float4*>(s);
  }
}

// =====================================================================
// 256x256 GEMM, counted-vmcnt 4-phase schedule, deep prefetch:
// C = A[M,K] * B[N,K]^T, 512 threads = 8 waves (2M x 4N), BK=64,
// 128KiB dbuf LDS, st_16x32 swizzle.
// Stage groups (4 gl_lds each, per wave): H0 = kh0 halves, H1 = kh1 halves.
// Issue schedule: prologue H0(0),H1(0),H0(1); then H1(t+1)@P1(t),
// H0(t+2)@P3(t) -- H0(t+2) lands in buf[t&1] kh0 regions, which are fully
// consumed by P1/P2(t) reads (all covered by the P3(t) barrier).
// Waits: P1 vmcnt(8) (younger: H1(t),H0(t+1)), P3 vmcnt(8) (younger:
// H0(t+1),H1(t+1)); tails vmcnt(4)/vmcnt(0). Every load gets a 6-phase
// latency window; no vmcnt(0) in steady state; 2 barriers/tile.
// =====================================================================
#define READ_A4(QA, KS, Ab)                                                   \
  _Pragma("unroll") for (int mi = 0; mi < 4; mi++)                            \
    af[mi] = *reinterpret_cast<const bf16x8*>(                                \
        (Ab) + aoff + ((((QA)*4 + mi)*2) + (KS))*512);

#define READ_B4(KS, Bb)                                                       \
  _Pragma("unroll") for (int ni = 0; ni < 4; ni++)                            \
    bfr[ni] = *reinterpret_cast<const bf16x8*>(                               \
        (Bb) + boff + ((ni*2) + (KS))*512);

#define MFMA16(QA)                                                            \
  _Pragma("unroll") for (int mi = 0; mi < 4; mi++)                            \
  _Pragma("unroll") for (int ni = 0; ni < 4; ni++)                            \
    acc[(QA)*4 + mi][ni] = __builtin_amdgcn_mfma_f32_16x16x32_bf16(           \
        af[mi], bfr[ni], acc[(QA)*4 + mi][ni], 0, 0, 0);

#define STAGE_H0(An, Bn, koff)                                                \
  gl_lds16(agA + (koff),           (An) + wid*1024);                          \
  gl_lds16(agA + 128*la + (koff),  (An) + (wid + 8)*1024);                    \
  gl_lds16(agB + (koff),           (Bn) + wid*1024);                          \
  gl_lds16(agB + 128*lb + (koff),  (Bn) + (wid + 8)*1024);

#define STAGE_H1(An, Bn, koff)                                                \
  gl_lds16(agA + (koff) + 32,          (An) + wid*1024 + 512);                \
  gl_lds16(agA + 128*la + (koff) + 32, (An) + (wid + 8)*1024 + 512);          \
  gl_lds16(agB + (koff) + 32,          (Bn) + wid*1024 + 512);                \
  gl_lds16(agB + 128*lb + (koff) + 32, (Bn) + (wid + 8)*1024 + 512);

template <typename CT, bool BIAS, bool ACCUM>
__global__ __launch_bounds__(512, 2) void gemm256(const bf16* __restrict__ A,
                                                  const bf16* __restrict__ Bm,
                                                  const float* __restrict__ bias,
                                                  CT* __restrict__ C,
                                                  int M, int N, int K,
                                                  long la, long lb, long lc,
                                                  long za, long zb, long zc) {
  extern __shared__ __align__(16) bf16 lds[];   // 65536 elems = 128 KiB
  const int z = blockIdx.z;
  A  += (long)z * za;
  Bm += (long)z * zb;
  C  += (long)z * zc;
  const int tid  = threadIdx.x;
  const int wid  = tid >> 6;
  const int lane = tid & 63;
  const int wm0 = (wid >> 2) * 128;     // wave row origin in 256-tile
  const int wn0 = (wid & 3) * 64;       // wave col origin
  const int m0 = blockIdx.y * 256, n0 = blockIdx.x * 256;

  // staging: lane -> (row rr, inverse-swizzled col cc) within a subtile
  const int rr = lane >> 2;
  const int cc = ((lane & 3) * 8) ^ ((rr & 8) << 1);
  const bf16* agA = A  + (long)(m0 + wid * 16 + rr) * la + cc;
  const bf16* agB = Bm + (long)(n0 + wid * 16 + rr) * lb + cc;

  // read-side per-lane base offsets (elems) incl. swizzle
  const int swz  = ((lane >> 4) * 8) ^ ((lane & 8) << 1);
  const int aoff = (wm0 >> 4) * 1024 + (lane & 15) * 32 + swz;
  const int boff = (wn0 >> 4) * 1024 + (lane & 15) * 32 + swz;

  f32x4 acc[8][4] = {};
  const int NT = K >> 6;

  // prologue: H0(0), H1(0) into buf0; H0(1) into buf1
  { bf16* An = lds; bf16* Bn = lds + 16384;
    STAGE_H0(An, Bn, 0); STAGE_H1(An, Bn, 0); }
  { bf16* An = lds + 32768; bf16* Bn = lds + 49152;
    STAGE_H0(An, Bn, 64); }

  for (int t = 0; t < NT; ++t) {
    const bf16* Ab = lds + (t & 1) * 32768;
    const bf16* Bb = Ab + 16384;
    bf16* An1 = lds + ((t & 1) ^ 1) * 32768;  // buf for tile t+1
    bf16* Bn1 = An1 + 16384;
    bf16* An2 = lds + (t & 1) * 32768;        // buf for tile t+2 (current buf)
    bf16* Bn2 = An2 + 16384;
    const bool pf1 = (t + 1) < NT;
    const bool pf2 = (t + 2) < NT;
    bf16x8 af[4], bfr[4];

    // ---- P1: kh=0, rows wm0..+63; need H0(t) drained
    if (pf1) asm volatile("s_waitcnt vmcnt(8)" ::: "memory");
    else     asm volatile("s_waitcnt vmcnt(4)" ::: "memory");
    __builtin_amdgcn_s_barrier();
    READ_A4(0, 0, Ab); READ_B4(0, Bb);
    if (pf1) { STAGE_H1(An1, Bn1, (long)(t + 1) * 64); }
    asm volatile("s_waitcnt lgkmcnt(0)" ::: "memory");
    __builtin_amdgcn_sched_barrier(0);
    __builtin_amdgcn_s_setprio(1); MFMA16(0); __builtin_amdgcn_s_setprio(0);

    // ---- P2: kh=0, rows wm0+64..+127 (data synced at P1)
    READ_A4(1, 0, Ab);
    asm volatile("s_waitcnt lgkmcnt(0)" ::: "memory");
    __builtin_amdgcn_sched_barrier(0);
    __builtin_amdgcn_s_setprio(1); MFMA16(1); __builtin_amdgcn_s_setprio(0);

    // ---- P3: kh=1; need H1(t) drained; kh0 of current buf now dead ->
    //          stage H0(t+2) into it
    if (pf1) asm volatile("s_waitcnt vmcnt(8)" ::: "memory");
    else     asm volatile("s_waitcnt vmcnt(0)" ::: "memory");
    __builtin_amdgcn_s_barrier();
    READ_A4(0, 1, Ab); READ_B4(1, Bb);
    if (pf2) { STAGE_H0(An2, Bn2, (long)(t + 2) * 64); }
    asm volatile("s_waitcnt lgkmcnt(0)" ::: "memory");
    __builtin_amdgcn_sched_barrier(0);
    __builtin_amdgcn_s_setprio(1); MFMA16(0); __builtin_amdgcn_s_setprio(0);

    // ---- P4: kh=1, rows wm0+64..+127
    READ_A4(1, 1, Ab);
    asm volatile("s_waitcnt lgkmcnt(0)" ::: "memory");
    __builtin_amdgcn_sched_barrier(0);
    __builtin_amdgcn_s_setprio(1); MFMA16(1); __builtin_amdgcn_s_setprio(0);
  }

#pragma unroll
  for (int mi = 0; mi < 8; mi++) {
#pragma unroll
    for (int ni = 0; ni < 4; ni++) {
      const int col = n0 + wn0 + ni * 16 + (lane & 15);
      float bv = 0.0f;
      if constexpr (BIAS) bv = bias[col];
      const long base = (long)(m0 + wm0 + mi * 16 + (lane >> 4) * 4) * lc + col;
#pragma unroll
      for (int r = 0; r < 4; r++) {
        float v = acc[mi][ni][r] + bv;
        if constexpr (ACCUM) v += (float)C[base + (long)r * lc];
        C[base + (long)r * lc] = (CT)v;
      }
    }
  }
}

// ---------- m97-style 128^2 GEMM (kept for small shapes: W2) ----------
template <typename CT, bool BIAS, bool ACCUM>
__global__ __launch_bounds__(256) void gemm_bt(const bf16* __restrict__ A,
                                               const bf16* __restrict__ Bm,
                                               const float* __restrict__ bias,
                                               CT* __restrict__ C,
                                               int M, int N, int K,
                                               long la, long lb, long lc,
                                               long za, long zb, long zc) {
  __shared__ __align__(16) bf16 As[128 * 32];
  __shared__ __align__(16) bf16 Bs[128 * 32];
  const int z = blockIdx.z;
  A  += (long)z * za;
  Bm += (long)z * zb;
  C  += (long)z * zc;
  const int tid = threadIdx.x;
  const int w = tid >> 6, l = tid & 63;
  const int wm = (w & 1) * 64, wn = (w >> 1) * 64;
  const int m0 = blockIdx.y * 128, n0 = blockIdx.x * 128;
  const int lr = l & 15, lk = (l >> 4) * 8;
  const int er = (l >> 4) * 4;

  const bf16* ag = A  + (long)(m0 + (tid >> 2)) * la + (tid & 3) * 8;
  const bf16* bg = Bm + (long)(n0 + (tid >> 2)) * lb + (tid & 3) * 8;
  bf16* al = As + (w * 16) * 32;
  bf16* bl = Bs + (w * 16) * 32;

  f32x4 acc[4][4] = {};

  for (int k0 = 0; k0 < K; k0 += 32) {
    gl_lds16(ag + k0,            al);
    gl_lds16(ag + 64 * la + k0,  al + 64 * 32);
    gl_lds16(bg + k0,            bl);
    gl_lds16(bg + 64 * lb + k0,  bl + 64 * 32);
    __syncthreads();
    bf16x8 afr[4], bfr[4];
#pragma unroll
    for (int mi = 0; mi < 4; mi++)
      afr[mi] = *reinterpret_cast<const bf16x8*>(As + (wm + mi * 16 + lr) * 32 + lk);
#pragma unroll
    for (int ni = 0; ni < 4; ni++)
      bfr[ni] = *reinterpret_cast<const bf16x8*>(Bs + (wn + ni * 16 + lr) * 32 + lk);
#pragma unroll
    for (int mi = 0; mi < 4; mi++)
#pragma unroll
      for (int ni = 0; ni < 4; ni++)
        acc[mi][ni] = __builtin_amdgcn_mfma_f32_16x16x32_bf16(afr[mi], bfr[ni], acc[mi][ni], 0, 0, 0);
    __syncthreads();
  }

#pragma unroll
  for (int mi = 0; mi < 4; mi++) {
#pragma unroll
    for (int ni = 0; ni < 4; ni++) {
      const int col = n0 + wn + ni * 16 + lr;
      float bv = 0.0f;
      if constexpr (BIAS) bv = bias[col];
      const long base = (long)(m0 + wm + mi * 16 + er) * lc + col;
#pragma unroll
      for (int r = 0; r < 4; r++) {
        float v = acc[mi][ni][r] + bv;
        if constexpr (ACCUM) v += (float)C[base + (long)r * lc];
        C[base + (long)r * lc] = (CT)v;
      }
    }
  }
}

// ---------- in-place RoPE on Q/K (first 64 dims of each head) ----------
__global__ __launch_bounds__(256) void rope_qk(bf16* __restrict__ QKV,
                                               const float* __restrict__ ch,
                                               const float* __restrict__ sh) {
  int idx = blockIdx.x * 256 + threadIdx.x;
  if (idx >= NROW * H_ * 2 * 32) return;
  int hd = idx & 31;
  int qk = (idx >> 5) & 1;
  int h  = (idx >> 6) & 15;
  int row = idx >> 10;             // 0..8191 = (b,s)
  int s = row & (S_ - 1);
  long base = (long)row * NQKV + qk * 2048 + h * HD_ + hd;
  float a  = (float)QKV[base];
  float b2 = (float)QKV[base + 32];
  float c = ch[s * 32 + hd], sn = sh[s * 32 + hd];
  QKV[base]      = (bf16)(a * c - b2 * sn);
  QKV[base + 32] = (bf16)(b2 * c + a * sn);
}

// ---------- K/V transpose: QKV K/V-region (b,s,h,hd) -> Xt[b,h,hd,t] --------
__global__ __launch_bounds__(256) void kvtrans(const bf16* __restrict__ QKV,
                                               bf16* __restrict__ Kt,
                                               bf16* __restrict__ Vt) {
  __shared__ unsigned short T[128 * 130];
  const int bid = blockIdx.x;          // kv*1024 + bh*8 + tb
  const int tb = bid & 7, bh = (bid >> 3) & 127, kv = bid >> 10;
  const int b = bh >> 4, h = bh & 15;
  const int tid = threadIdx.x;
  const bf16* src = QKV + (long)(b * S_ + tb * 128) * NQKV + 2048 + kv * 2048 + h * HD_;
#pragma unroll
  for (int it = 0; it < 8; it++) {
    int chunk = it * 256 + tid;
    int r = chunk >> 4, hc = (chunk & 15) * 8;
    bf16x8 v = *reinterpret_cast<const bf16x8*>(src + (long)r * NQKV + hc);
    union { bf16x8 v8; unsigned short u[8]; } u8; u8.v8 = v;
#pragma unroll
    for (int j = 0; j < 8; j++) T[r * 130 + hc + j] = u8.u[j];
  }
  __syncthreads();
  bf16* dst = (kv ? Vt : Kt) + (long)bh * HD_ * S_ + tb * 128;
#pragma unroll
  for (int it = 0; it < 8; it++) {
    int chunk = it * 256 + tid;
    int hd = chunk >> 4, tc = (chunk & 15) * 8;
    union { bf16x8 v8; unsigned short u[8]; } u8;
#pragma unroll
    for (int j = 0; j < 8; j++) u8.u[j] = T[(tc + j) * 130 + hd];
    *reinterpret_cast<bf16x8*>(dst + (long)hd * S_ + tc) = u8.v8;
  }
}

// ---------- Ob += Q * W2^T per (b,h):  M=1024(s) N=128(d) K=128(e) ----------
__global__ __launch_bounds__(256) void qw2_gemm(const bf16* __restrict__ QKV,
                                                const bf16* __restrict__ W2,
                                                bf16* __restrict__ Ob) {
  __shared__ __align__(16) bf16 As[128 * 32];
  __shared__ __align__(16) bf16 Bs[128 * 32];
  const int z = blockIdx.z;            // bh
  const int b = z >> 4, h = z & 15;
  const int m0 = blockIdx.y * 128;
  const int tid = threadIdx.x;
  const int w = tid >> 6, l = tid & 63;
  const int wm = (w & 1) * 64, wn = (w >> 1) * 64;
  const int lr = l & 15, lk = (l >> 4) * 8;
  const int er = (l >> 4) * 4;

  const bf16* ag = QKV + (long)(b * S_ + m0 + (tid >> 2)) * NQKV + h * HD_ + (tid & 3) * 8;
  const bf16* bg = W2 + (long)z * (HD_ * HD_) + (tid >> 2) * HD_ + (tid & 3) * 8;
  bf16* al = As + (w * 16) * 32;
  bf16* bl = Bs + (w * 16) * 32;

  f32x4 acc[4][4] = {};

#pragma unroll
  for (int k0 = 0; k0 < HD_; k0 += 32) {
    gl_lds16(ag + k0,                   al);
    gl_lds16(ag + (long)64 * NQKV + k0, al + 64 * 32);
    gl_lds16(bg + k0,                   bl);
    gl_lds16(bg + 64 * HD_ + k0,        bl + 64 * 32);
    __syncthreads();
    bf16x8 afr[4], bfr[4];
#pragma unroll
    for (int mi = 0; mi < 4; mi++)
      afr[mi] = *reinterpret_cast<const bf16x8*>(As + (wm + mi * 16 + lr) * 32 + lk);
#pragma unroll
    for (int ni = 0; ni < 4; ni++)
      bfr[ni] = *reinterpret_cast<const bf16x8*>(Bs + (wn + ni * 16 + lr) * 32 + lk);
#pragma unroll
    for (int mi = 0; mi < 4; mi++)
#pragma unroll
      for (int ni = 0; ni < 4; ni++)
        acc[mi][ni] = __builtin_amdgcn_mfma_f32_16x16x32_bf16(afr[mi], bfr[ni], acc[mi][ni], 0, 0, 0);
    __syncthreads();
  }

#pragma unroll
  for (int mi = 0; mi < 4; mi++) {
#pragma unroll
    for (int ni = 0; ni < 4; ni++) {
      const int col = h * HD_ + wn + ni * 16 + lr;
#pragma unroll
      for (int r = 0; r < 4; r++) {
        const int sl = m0 + wm + mi * 16 + er + r;
        const long idx = (long)(b * S_ + sl) * D_ + col;
        Ob[idx] = (bf16)((float)Ob[idx] + acc[mi][ni][r]);
      }
    }
  }
}

extern "C" void kernel_launch(void* const* d_in, const int* in_sizes, int n_in,
                              void* d_out, int out_size, void* d_ws, size_t ws_size,
                              hipStream_t stream) {
  const float* x   = (const float*)d_in[0];
  const float* wq  = (const float*)d_in[1];
  const float* bq  = (const float*)d_in[2];
  const float* wk  = (const float*)d_in[3];
  const float* bk  = (const float*)d_in[4];
  const float* wv  = (const float*)d_in[5];
  const float* bv  = (const float*)d_in[6];
  const float* wo  = (const float*)d_in[7];
  const float* bo  = (const float*)d_in[8];
  const float* ch  = (const float*)d_in[9];
  const float* sh  = (const float*)d_in[10];
  const float* mask = (const float*)d_in[11];
  float* out = (float*)d_out;

  // allow 128 KiB dynamic LDS for the 256^2 kernels
  hipFuncSetAttribute(reinterpret_cast<const void*>(&gemm256<bf16, true, false>),
                      hipFuncAttributeMaxDynamicSharedMemorySize, 131072);
  hipFuncSetAttribute(reinterpret_cast<const void*>(&gemm256<bf16, false, false>),
                      hipFuncAttributeMaxDynamicSharedMemorySize, 131072);
  hipFuncSetAttribute(reinterpret_cast<const void*>(&gemm256<float, true, false>),
                      hipFuncAttributeMaxDynamicSharedMemorySize, 131072);

  char* ws = (char*)d_ws;
  bf16*  QKV   = (bf16*)(ws);                    // 96 MB
  bf16*  Vt    = (bf16*)(ws + 100663296);        // 32 MB
  bf16*  Kt    = (bf16*)(ws + 134217728);        // 32 MB
  bf16*  wob   = (bf16*)(ws + 167772160);        // 8 MB
  float* bqkv  = (float*)(ws + 176160768);       // 24 KB
  bf16*  maskb = (bf16*)(ws + 176185344);        // 2 MB
  bf16*  W2    = (bf16*)(ws + 178282496);        // 4 MB
  bf16*  Ob    = (bf16*)(ws + 182476800);        // 32 MB
  bf16*  xb    = (bf16*)(ws + 216031232);        // 32 MB (dead after GEMM1)
  bf16*  wqkvb = (bf16*)(ws + 249585664);        // 24 MB (dead after GEMM1)

  // fused conversions + bias pack (one launch; 8652288 float4-units / 256)
  prep<<<33798, 256, 0, stream>>>(x, wq, wk, wv, wo, mask, bq, bk, bv,
                                  xb, wqkvb, wob, maskb, bqkv);

  // QKV = x @ [wq;wk;wv]^T + bias  (8192 x 6144 x 2048)
  gemm256<bf16, true, false><<<dim3(24, 32, 1), 512, 131072, stream>>>(
      xb, wqkvb, bqkv, QKV, NROW, NQKV, D_,
      (long)D_, (long)D_, (long)NQKV, 0L, 0L, 0L);

  rope_qk<<<32768, 256, 0, stream>>>(QKV, ch, sh);
  kvtrans<<<2048, 256, 0, stream>>>(QKV, Kt, Vt);

  // W2[bh][d][e] = sum_t V[t,d] K[t,e]   (128 batches of 128x128xK=1024)
  gemm_bt<bf16, false, false><<<dim3(1, 1, 128), 256, 0, stream>>>(
      Vt, Kt, nullptr, W2, HD_, HD_, S_,
      (long)S_, (long)S_, (long)HD_,
      (long)(HD_ * S_), (long)(HD_ * S_), (long)(HD_ * HD_));

  // Ob = mask @ V  per batch  (8 batches of 1024 x 2048 x K=1024)
  gemm256<bf16, false, false><<<dim3(8, 4, 8), 512, 131072, stream>>>(
      maskb, Vt, nullptr, Ob, S_, D_, S_,
      (long)S_, (long)S_, (long)D_,
      0L, (long)(D_ * S_), (long)(S_ * D_));

  // Ob += Q @ W2^T  per (b,h)  (128 batches of 1024 x 128 x K=128)
  qw2_gemm<<<dim3(1, 8, 128), 256, 0, stream>>>(QKV, W2, Ob);

  // out = a_sum @ wo^T + bo  (8192 x 2048 x 2048, fp32 output)
  gemm256<float, true, false><<<dim3(8, 32, 1), 512, 131072, stream>>>(
      Ob, wob, bo, out, NROW, D_, D_,
      (long)D_, (long)D_, (long)D_, 0L, 0L, 0L);
}

// Round 7
// 605.175 us; speedup vs baseline: 1.2880x; 1.0415x over previous
//
#include <hip/hip_runtime.h>
#include <stdint.h>

#define B_ 8
#define S_ 1024
#define D_ 2048
#define H_ 16
#define HD_ 128
#define NROW 8192      // B_*S_
#define NQKV 6144      // 3*D_

typedef __bf16 bf16;
typedef bf16  bf16x8 __attribute__((ext_vector_type(8)));
typedef bf16  bf16x4 __attribute__((ext_vector_type(4)));
typedef float f32x4  __attribute__((ext_vector_type(4)));

#define AS1 __attribute__((address_space(1)))
#define AS3 __attribute__((address_space(3)))

// async global->LDS, 16B per lane; LDS dest = wave-uniform base + lane*16
__device__ __forceinline__ void gl_lds16(const bf16* g, bf16* l) {
  __builtin_amdgcn_global_load_lds((AS1 void*)g, (AS3 void*)l, 16, 0, 0);
}

// ---------- fused input prep: all fp32->bf16 conversions + bias pack --------
__global__ __launch_bounds__(256) void prep(const float* __restrict__ x,
                                            const float* __restrict__ wq,
                                            const float* __restrict__ wk,
                                            const float* __restrict__ wv,
                                            const float* __restrict__ wo,
                                            const float* __restrict__ mask,
                                            const float* __restrict__ bq,
                                            const float* __restrict__ bk,
                                            const float* __restrict__ bv,
                                            bf16* __restrict__ xb,
                                            bf16* __restrict__ wqkvb,
                                            bf16* __restrict__ wob,
                                            bf16* __restrict__ maskb,
                                            float* __restrict__ bqkv) {
  long i = (long)blockIdx.x * 256 + threadIdx.x;
  if (i < 8650752) {
    const float* src; bf16* dst; long j;
    if (i < 4194304)      { src = x;    dst = xb;              j = i; }
    else if (i < 5242880) { src = wq;   dst = wqkvb;           j = i - 4194304; }
    else if (i < 6291456) { src = wk;   dst = wqkvb + 4194304; j = i - 5242880; }
    else if (i < 7340032) { src = wv;   dst = wqkvb + 8388608; j = i - 6291456; }
    else if (i < 8388608) { src = wo;   dst = wob;             j = i - 7340032; }
    else                  { src = mask; dst = maskb;           j = i - 8388608; }
    float4 v = reinterpret_cast<const float4*>(src)[j];
    bf16x4 o;
    o.x = (bf16)v.x; o.y = (bf16)v.y; o.z = (bf16)v.z; o.w = (bf16)v.w;
    reinterpret_cast<bf16x4*>(dst)[j] = o;
  } else {
    long e = (i - 8650752) * 4;
    const float* s = (e < 2048) ? bq + e : (e < 4096 ? bk + (e - 2048) : bv + (e - 4096));
    *reinterpret_cast<float4*>(bqkv + e) = *reinterpret_cast<const float4*>(s);
  }
}

// =====================================================================
// 256x256 GEMM, round-4 counted-vmcnt schedule (best measured: 192.5us
// on QKV): C = A[M,K]*B[N,K]^T, 8 waves (2Mx4N), BK=64, 128KiB dbuf LDS,
// st_16x32 swizzle. H0/H1 = kh0/kh1 stage groups (4 gl_lds each/wave).
// P1: vmcnt(4) [H0(t) landed], stage H0(t+1). P3: vmcnt(4) [H1(t)
// landed], stage H1(t+1). 2 barriers/tile, no vmcnt(0) in steady state.
// ROPE: fused rotary embedding on Q/K head dims 0..63 in the epilogue
// (pairs (hd,hd+32) = frags (ni,ni+2), per-lane fp32, bias first).
// =====================================================================
#define READ_A4(QA, KS, Ab)                                                   \
  _Pragma("unroll") for (int mi = 0; mi < 4; mi++)                            \
    af[mi] = *reinterpret_cast<const bf16x8*>(                                \
        (Ab) + aoff + ((((QA)*4 + mi)*2) + (KS))*512);

#define READ_B4(KS, Bb)                                                       \
  _Pragma("unroll") for (int ni = 0; ni < 4; ni++)                            \
    bfr[ni] = *reinterpret_cast<const bf16x8*>(                               \
        (Bb) + boff + ((ni*2) + (KS))*512);

#define MFMA16(QA)                                                            \
  _Pragma("unroll") for (int mi = 0; mi < 4; mi++)                            \
  _Pragma("unroll") for (int ni = 0; ni < 4; ni++)                            \
    acc[(QA)*4 + mi][ni] = __builtin_amdgcn_mfma_f32_16x16x32_bf16(           \
        af[mi], bfr[ni], acc[(QA)*4 + mi][ni], 0, 0, 0);

#define STAGE_H0(An, Bn, koff)                                                \
  gl_lds16(agA + (koff),           (An) + wid*1024);                          \
  gl_lds16(agA + 128*la + (koff),  (An) + (wid + 8)*1024);                    \
  gl_lds16(agB + (koff),           (Bn) + wid*1024);                          \
  gl_lds16(agB + 128*lb + (koff),  (Bn) + (wid + 8)*1024);

#define STAGE_H1(An, Bn, koff)                                                \
  gl_lds16(agA + (koff) + 32,          (An) + wid*1024 + 512);                \
  gl_lds16(agA + 128*la + (koff) + 32, (An) + (wid + 8)*1024 + 512);          \
  gl_lds16(agB + (koff) + 32,          (Bn) + wid*1024 + 512);                \
  gl_lds16(agB + 128*lb + (koff) + 32, (Bn) + (wid + 8)*1024 + 512);

// main K-loop body, shared by gemm256 and pv256
#define GEMM256_MAIN_LOOP(NT)                                                 \
  { bf16* An = lds; bf16* Bn = lds + 16384;                                   \
    STAGE_H0(An, Bn, 0); STAGE_H1(An, Bn, 0); }                               \
  for (int t = 0; t < (NT); ++t) {                                            \
    const bf16* Ab = lds + (t & 1) * 32768;                                   \
    const bf16* Bb = Ab + 16384;                                              \
    bf16* An = lds + ((t & 1) ^ 1) * 32768;                                   \
    bf16* Bn = An + 16384;                                                    \
    const long kn = (long)(t + 1) * 64;                                       \
    const bool pf = (t + 1) < (NT);                                           \
    bf16x8 af[4], bfr[4];                                                     \
    asm volatile("s_waitcnt vmcnt(4)" ::: "memory");                          \
    __builtin_amdgcn_s_barrier();                                             \
    READ_A4(0, 0, Ab); READ_B4(0, Bb);                                        \
    if (pf) { STAGE_H0(An, Bn, kn); }                                         \
    asm volatile("s_waitcnt lgkmcnt(0)" ::: "memory");                        \
    __builtin_amdgcn_sched_barrier(0);                                        \
    __builtin_amdgcn_s_setprio(1); MFMA16(0); __builtin_amdgcn_s_setprio(0);  \
    READ_A4(1, 0, Ab);                                                        \
    asm volatile("s_waitcnt lgkmcnt(0)" ::: "memory");                        \
    __builtin_amdgcn_sched_barrier(0);                                        \
    __builtin_amdgcn_s_setprio(1); MFMA16(1); __builtin_amdgcn_s_setprio(0);  \
    if (pf) asm volatile("s_waitcnt vmcnt(4)" ::: "memory");                  \
    else    asm volatile("s_waitcnt vmcnt(0)" ::: "memory");                  \
    __builtin_amdgcn_s_barrier();                                             \
    READ_A4(0, 1, Ab); READ_B4(1, Bb);                                        \
    if (pf) { STAGE_H1(An, Bn, kn); }                                         \
    asm volatile("s_waitcnt lgkmcnt(0)" ::: "memory");                        \
    __builtin_amdgcn_sched_barrier(0);                                        \
    __builtin_amdgcn_s_setprio(1); MFMA16(0); __builtin_amdgcn_s_setprio(0);  \
    READ_A4(1, 1, Ab);                                                        \
    asm volatile("s_waitcnt lgkmcnt(0)" ::: "memory");                        \
    __builtin_amdgcn_sched_barrier(0);                                        \
    __builtin_amdgcn_s_setprio(1); MFMA16(1); __builtin_amdgcn_s_setprio(0);  \
  }

template <typename CT, bool BIAS, bool ACCUM, bool ROPE>
__global__ __launch_bounds__(512, 2) void gemm256(const bf16* __restrict__ A,
                                                  const bf16* __restrict__ Bm,
                                                  const float* __restrict__ bias,
                                                  CT* __restrict__ C,
                                                  int M, int N, int K,
                                                  long la, long lb, long lc,
                                                  long za, long zb, long zc,
                                                  const float* __restrict__ chp,
                                                  const float* __restrict__ shp) {
  extern __shared__ __align__(16) bf16 lds[];   // 65536 elems = 128 KiB
  const int z = blockIdx.z;
  A  += (long)z * za;
  Bm += (long)z * zb;
  C  += (long)z * zc;
  const int tid  = threadIdx.x;
  const int wid  = tid >> 6;
  const int lane = tid & 63;
  const int wm0 = (wid >> 2) * 128;
  const int wn0 = (wid & 3) * 64;
  const int m0 = blockIdx.y * 256, n0 = blockIdx.x * 256;

  const int rr = lane >> 2;
  const int cc = ((lane & 3) * 8) ^ ((rr & 8) << 1);
  const bf16* agA = A  + (long)(m0 + wid * 16 + rr) * la + cc;
  const bf16* agB = Bm + (long)(n0 + wid * 16 + rr) * lb + cc;

  const int swz  = ((lane >> 4) * 8) ^ ((lane & 8) << 1);
  const int aoff = (wm0 >> 4) * 1024 + (lane & 15) * 32 + swz;
  const int boff = (wn0 >> 4) * 1024 + (lane & 15) * 32 + swz;

  f32x4 acc[8][4] = {};
  const int NT = K >> 6;

  GEMM256_MAIN_LOOP(NT);

#pragma unroll
  for (int mi = 0; mi < 8; mi++) {
    float vals[4][4];
#pragma unroll
    for (int ni = 0; ni < 4; ni++) {
      const int col = n0 + wn0 + ni * 16 + (lane & 15);
      float bv = 0.0f;
      if constexpr (BIAS) bv = bias[col];
#pragma unroll
      for (int r = 0; r < 4; r++) vals[ni][r] = acc[mi][ni][r] + bv;
    }
    if constexpr (ROPE) {
      // Q/K head dims 0..63: (hd, hd+32) = (ni, ni+2), same lane
      if ((n0 + wn0) < 4096 && (((n0 + wn0) & 127) == 0)) {
#pragma unroll
        for (int ni = 0; ni < 2; ni++)
#pragma unroll
          for (int r = 0; r < 4; r++) {
            const int srow = (m0 + wm0 + mi * 16 + (lane >> 4) * 4 + r) & (S_ - 1);
            const int hd = ni * 16 + (lane & 15);
            const float c  = chp[srow * 32 + hd];
            const float sn = shp[srow * 32 + hd];
            const float a  = vals[ni][r], b2 = vals[ni + 2][r];
            vals[ni][r]     = a * c - b2 * sn;
            vals[ni + 2][r] = b2 * c + a * sn;
          }
      }
    }
#pragma unroll
    for (int ni = 0; ni < 4; ni++) {
      const int col = n0 + wn0 + ni * 16 + (lane & 15);
      const long base = (long)(m0 + wm0 + mi * 16 + (lane >> 4) * 4) * lc + col;
#pragma unroll
      for (int r = 0; r < 4; r++) {
        float v = vals[ni][r];
        if constexpr (ACCUM) v += (float)C[base + (long)r * lc];
        C[base + (long)r * lc] = (CT)v;
      }
    }
  }
}

// =====================================================================
// pv256: Ob[b] = mask @ V_b  (K=1024 main loop)  +  Q_b @ W2_b^T (K2=128
// tail fused; per-wave head is uniform since a 64-col wave span sits
// inside one 128-col head). Grid (8,4,8): x=col tile, y=row tile, z=b.
// K2 LDS: A2h0[0,16384) A2h1[16384,32768) = Q 256rows x 64e per head;
// B2h0[32768,40960) B2h1[40960,49152) = W2 128d x 64e per head.
// =====================================================================
__global__ __launch_bounds__(512, 2) void pv256(const bf16* __restrict__ Am,
                                                const bf16* __restrict__ Vt,
                                                const bf16* __restrict__ QKV,
                                                const bf16* __restrict__ W2,
                                                bf16* __restrict__ Ob) {
  extern __shared__ __align__(16) bf16 lds[];
  const int z = blockIdx.z;                    // batch b
  const bf16* A  = Am;                         // mask (shared over b)
  const bf16* Bm = Vt + (long)z * (D_ * S_);
  bf16* C = Ob + (long)z * (S_ * D_);
  const long la = S_, lb = S_;
  const int tid  = threadIdx.x;
  const int wid  = tid >> 6;
  const int lane = tid & 63;
  const int wm0 = (wid >> 2) * 128;
  const int wn0 = (wid & 3) * 64;
  const int m0 = blockIdx.y * 256, n0 = blockIdx.x * 256;

  const int rr = lane >> 2;
  const int cc = ((lane & 3) * 8) ^ ((rr & 8) << 1);
  const bf16* agA = A  + (long)(m0 + wid * 16 + rr) * la + cc;
  const bf16* agB = Bm + (long)(n0 + wid * 16 + rr) * lb + cc;

  const int swz  = ((lane >> 4) * 8) ^ ((lane & 8) << 1);
  const int aoff = (wm0 >> 4) * 1024 + (lane & 15) * 32 + swz;
  const int boff = (wn0 >> 4) * 1024 + (lane & 15) * 32 + swz;

  f32x4 acc[8][4] = {};

  GEMM256_MAIN_LOOP(16);

  // ---------------- K2 tail: acc += Q[.,h*128+e] * W2[h][d][e]^T ----------
  const int h0 = n0 >> 7;                      // first head of this block
  const int hsel = wn0 >> 7;                   // this wave's head offset 0/1
  const int a2base = hsel * 16384;
  const int b2base = 32768 + hsel * 8192;
  const int bsub = (wn0 & 64) >> 4;            // 0 or 4 (d-row subtile base)
  const int a2off = (wm0 >> 4) * 1024 + (lane & 15) * 32 + swz;
  const int b2off = (lane & 15) * 32 + swz;

#define STAGE_K2(e0)                                                          \
  { const bf16* qa0 = QKV + (long)(z * S_ + m0 + wid * 16 + rr) * NQKV        \
                      + h0 * 128 + (e0) + cc;                                 \
    gl_lds16(qa0,                       lds + wid * 1024);                    \
    gl_lds16(qa0 + 32,                  lds + wid * 1024 + 512);              \
    gl_lds16(qa0 + 128 * NQKV,          lds + (wid + 8) * 1024);              \
    gl_lds16(qa0 + 128 * NQKV + 32,     lds + (wid + 8) * 1024 + 512);        \
    gl_lds16(qa0 + 128,                 lds + 16384 + wid * 1024);            \
    gl_lds16(qa0 + 160,                 lds + 16384 + wid * 1024 + 512);      \
    gl_lds16(qa0 + 128 * NQKV + 128,    lds + 16384 + (wid + 8) * 1024);      \
    gl_lds16(qa0 + 128 * NQKV + 160,    lds + 16384 + (wid + 8) * 1024 + 512);\
    const bf16* w0 = W2 + (long)(z * 16 + h0) * 16384                         \
                     + (wid * 16 + rr) * 128 + (e0) + cc;                     \
    gl_lds16(w0,                        lds + 32768 + wid * 1024);            \
    gl_lds16(w0 + 32,                   lds + 32768 + wid * 1024 + 512);      \
    gl_lds16(w0 + 16384,                lds + 40960 + wid * 1024);            \
    gl_lds16(w0 + 16384 + 32,           lds + 40960 + wid * 1024 + 512);      }

  __builtin_amdgcn_s_barrier();                // all waves past main-loop reads
  STAGE_K2(0);
#pragma unroll
  for (int step = 0; step < 2; step++) {
    asm volatile("s_waitcnt vmcnt(0)" ::: "memory");
    __builtin_amdgcn_s_barrier();
    bf16x8 a2[8], b2[4];
#pragma unroll
    for (int ks = 0; ks < 2; ks++) {
#pragma unroll
      for (int mi = 0; mi < 8; mi++)
        a2[mi] = *reinterpret_cast<const bf16x8*>(
            lds + a2base + a2off + mi * 1024 + ks * 512);
#pragma unroll
      for (int ni = 0; ni < 4; ni++)
        b2[ni] = *reinterpret_cast<const bf16x8*>(
            lds + b2base + b2off + (bsub + ni) * 1024 + ks * 512);
      asm volatile("s_waitcnt lgkmcnt(0)" ::: "memory");
      __builtin_amdgcn_sched_barrier(0);
      __builtin_amdgcn_s_setprio(1);
#pragma unroll
      for (int mi = 0; mi < 8; mi++)
#pragma unroll
        for (int ni = 0; ni < 4; ni++)
          acc[mi][ni] = __builtin_amdgcn_mfma_f32_16x16x32_bf16(
              a2[mi], b2[ni], acc[mi][ni], 0, 0, 0);
      __builtin_amdgcn_s_setprio(0);
    }
    if (step == 0) {
      __builtin_amdgcn_s_barrier();            // all waves done reading step0
      STAGE_K2(64);
    }
  }
#undef STAGE_K2

#pragma unroll
  for (int mi = 0; mi < 8; mi++) {
#pragma unroll
    for (int ni = 0; ni < 4; ni++) {
      const int col = n0 + wn0 + ni * 16 + (lane & 15);
      const long base = (long)(m0 + wm0 + mi * 16 + (lane >> 4) * 4) * D_ + col;
#pragma unroll
      for (int r = 0; r < 4; r++)
        C[base + (long)r * D_] = (bf16)acc[mi][ni][r];
    }
  }
}

// ---------- m97-style 128^2 GEMM (kept for small shapes: W2) ----------
template <typename CT, bool BIAS, bool ACCUM>
__global__ __launch_bounds__(256) void gemm_bt(const bf16* __restrict__ A,
                                               const bf16* __restrict__ Bm,
                                               const float* __restrict__ bias,
                                               CT* __restrict__ C,
                                               int M, int N, int K,
                                               long la, long lb, long lc,
                                               long za, long zb, long zc) {
  __shared__ __align__(16) bf16 As[128 * 32];
  __shared__ __align__(16) bf16 Bs[128 * 32];
  const int z = blockIdx.z;
  A  += (long)z * za;
  Bm += (long)z * zb;
  C  += (long)z * zc;
  const int tid = threadIdx.x;
  const int w = tid >> 6, l = tid & 63;
  const int wm = (w & 1) * 64, wn = (w >> 1) * 64;
  const int m0 = blockIdx.y * 128, n0 = blockIdx.x * 128;
  const int lr = l & 15, lk = (l >> 4) * 8;
  const int er = (l >> 4) * 4;

  const bf16* ag = A  + (long)(m0 + (tid >> 2)) * la + (tid & 3) * 8;
  const bf16* bg = Bm + (long)(n0 + (tid >> 2)) * lb + (tid & 3) * 8;
  bf16* al = As + (w * 16) * 32;
  bf16* bl = Bs + (w * 16) * 32;

  f32x4 acc[4][4] = {};

  for (int k0 = 0; k0 < K; k0 += 32) {
    gl_lds16(ag + k0,            al);
    gl_lds16(ag + 64 * la + k0,  al + 64 * 32);
    gl_lds16(bg + k0,            bl);
    gl_lds16(bg + 64 * lb + k0,  bl + 64 * 32);
    __syncthreads();
    bf16x8 afr[4], bfr[4];
#pragma unroll
    for (int mi = 0; mi < 4; mi++)
      afr[mi] = *reinterpret_cast<const bf16x8*>(As + (wm + mi * 16 + lr) * 32 + lk);
#pragma unroll
    for (int ni = 0; ni < 4; ni++)
      bfr[ni] = *reinterpret_cast<const bf16x8*>(Bs + (wn + ni * 16 + lr) * 32 + lk);
#pragma unroll
    for (int mi = 0; mi < 4; mi++)
#pragma unroll
      for (int ni = 0; ni < 4; ni++)
        acc[mi][ni] = __builtin_amdgcn_mfma_f32_16x16x32_bf16(afr[mi], bfr[ni], acc[mi][ni], 0, 0, 0);
    __syncthreads();
  }

#pragma unroll
  for (int mi = 0; mi < 4; mi++) {
#pragma unroll
    for (int ni = 0; ni < 4; ni++) {
      const int col = n0 + wn + ni * 16 + lr;
      float bv = 0.0f;
      if constexpr (BIAS) bv = bias[col];
      const long base = (long)(m0 + wm + mi * 16 + er) * lc + col;
#pragma unroll
      for (int r = 0; r < 4; r++) {
        float v = acc[mi][ni][r] + bv;
        if constexpr (ACCUM) v += (float)C[base + (long)r * lc];
        C[base + (long)r * lc] = (CT)v;
      }
    }
  }
}

// ---------- K/V transpose: QKV K/V-region (b,s,h,hd) -> Xt[b,h,hd,t] --------
__global__ __launch_bounds__(256) void kvtrans(const bf16* __restrict__ QKV,
                                               bf16* __restrict__ Kt,
                                               bf16* __restrict__ Vt) {
  __shared__ unsigned short T[128 * 130];
  const int bid = blockIdx.x;          // kv*1024 + bh*8 + tb
  const int tb = bid & 7, bh = (bid >> 3) & 127, kv = bid >> 10;
  const int b = bh >> 4, h = bh & 15;
  const int tid = threadIdx.x;
  const bf16* src = QKV + (long)(b * S_ + tb * 128) * NQKV + 2048 + kv * 2048 + h * HD_;
#pragma unroll
  for (int it = 0; it < 8; it++) {
    int chunk = it * 256 + tid;
    int r = chunk >> 4, hc = (chunk & 15) * 8;
    bf16x8 v = *reinterpret_cast<const bf16x8*>(src + (long)r * NQKV + hc);
    union { bf16x8 v8; unsigned short u[8]; } u8; u8.v8 = v;
#pragma unroll
    for (int j = 0; j < 8; j++) T[r * 130 + hc + j] = u8.u[j];
  }
  __syncthreads();
  bf16* dst = (kv ? Vt : Kt) + (long)bh * HD_ * S_ + tb * 128;
#pragma unroll
  for (int it = 0; it < 8; it++) {
    int chunk = it * 256 + tid;
    int hd = chunk >> 4, tc = (chunk & 15) * 8;
    union { bf16x8 v8; unsigned short u[8]; } u8;
#pragma unroll
    for (int j = 0; j < 8; j++) u8.u[j] = T[(tc + j) * 130 + hd];
    *reinterpret_cast<bf16x8*>(dst + (long)hd * S_ + tc) = u8.v8;
  }
}

extern "C" void kernel_launch(void* const* d_in, const int* in_sizes, int n_in,
                              void* d_out, int out_size, void* d_ws, size_t ws_size,
                              hipStream_t stream) {
  const float* x   = (const float*)d_in[0];
  const float* wq  = (const float*)d_in[1];
  const float* bq  = (const float*)d_in[2];
  const float* wk  = (const float*)d_in[3];
  const float* bk  = (const float*)d_in[4];
  const float* wv  = (const float*)d_in[5];
  const float* bv  = (const float*)d_in[6];
  const float* wo  = (const float*)d_in[7];
  const float* bo  = (const float*)d_in[8];
  const float* ch  = (const float*)d_in[9];
  const float* sh  = (const float*)d_in[10];
  const float* mask = (const float*)d_in[11];
  float* out = (float*)d_out;

  // allow 128 KiB dynamic LDS for the 256^2 kernels
  hipFuncSetAttribute(reinterpret_cast<const void*>(&gemm256<bf16, true, false, true>),
                      hipFuncAttributeMaxDynamicSharedMemorySize, 131072);
  hipFuncSetAttribute(reinterpret_cast<const void*>(&gemm256<float, true, false, false>),
                      hipFuncAttributeMaxDynamicSharedMemorySize, 131072);
  hipFuncSetAttribute(reinterpret_cast<const void*>(&pv256),
                      hipFuncAttributeMaxDynamicSharedMemorySize, 131072);

  char* ws = (char*)d_ws;
  bf16*  QKV   = (bf16*)(ws);                    // 96 MB
  bf16*  Vt    = (bf16*)(ws + 100663296);        // 32 MB
  bf16*  Kt    = (bf16*)(ws + 134217728);        // 32 MB
  bf16*  wob   = (bf16*)(ws + 167772160);        // 8 MB
  float* bqkv  = (float*)(ws + 176160768);       // 24 KB
  bf16*  maskb = (bf16*)(ws + 176185344);        // 2 MB
  bf16*  W2    = (bf16*)(ws + 178282496);        // 4 MB
  bf16*  Ob    = (bf16*)(ws + 182476800);        // 32 MB
  bf16*  xb    = (bf16*)(ws + 216031232);        // 32 MB (dead after GEMM1)
  bf16*  wqkvb = (bf16*)(ws + 249585664);        // 24 MB (dead after GEMM1)

  // fused conversions + bias pack
  prep<<<33798, 256, 0, stream>>>(x, wq, wk, wv, wo, mask, bq, bk, bv,
                                  xb, wqkvb, wob, maskb, bqkv);

  // QKV = x @ [wq;wk;wv]^T + bias, with RoPE fused into the epilogue
  gemm256<bf16, true, false, true><<<dim3(24, 32, 1), 512, 131072, stream>>>(
      xb, wqkvb, bqkv, QKV, NROW, NQKV, D_,
      (long)D_, (long)D_, (long)NQKV, 0L, 0L, 0L, ch, sh);

  kvtrans<<<2048, 256, 0, stream>>>(QKV, Kt, Vt);

  // W2[bh][d][e] = sum_t V[t,d] K[t,e]   (128 batches of 128x128xK=1024)
  gemm_bt<bf16, false, false><<<dim3(1, 1, 128), 256, 0, stream>>>(
      Vt, Kt, nullptr, W2, HD_, HD_, S_,
      (long)S_, (long)S_, (long)HD_,
      (long)(HD_ * S_), (long)(HD_ * S_), (long)(HD_ * HD_));

  // Ob = mask @ V + Q @ W2^T  (fused; 8 batches of 1024 x 2048)
  pv256<<<dim3(8, 4, 8), 512, 131072, stream>>>(maskb, Vt, QKV, W2, Ob);

  // out = a_sum @ wo^T + bo  (8192 x 2048 x 2048, fp32 output)
  gemm256<float, true, false, false><<<dim3(8, 32, 1), 512, 131072, stream>>>(
      Ob, wob, bo, out, NROW, D_, D_,
      (long)D_, (long)D_, (long)D_, 0L, 0L, 0L, nullptr, nullptr);
}

// Round 8
// 568.176 us; speedup vs baseline: 1.3718x; 1.0651x over previous
//
#include <hip/hip_runtime.h>
#include <stdint.h>

#define B_ 8
#define S_ 1024
#define D_ 2048
#define H_ 16
#define HD_ 128
#define NROW 8192      // B_*S_
#define NQKV 6144      // 3*D_

typedef __bf16 bf16;
typedef bf16  bf16x8 __attribute__((ext_vector_type(8)));
typedef bf16  bf16x4 __attribute__((ext_vector_type(4)));
typedef float f32x4  __attribute__((ext_vector_type(4)));

#define AS1 __attribute__((address_space(1)))
#define AS3 __attribute__((address_space(3)))

// async global->LDS, 16B per lane; LDS dest = wave-uniform base + lane*16
__device__ __forceinline__ void gl_lds16(const bf16* g, bf16* l) {
  __builtin_amdgcn_global_load_lds((AS1 void*)g, (AS3 void*)l, 16, 0, 0);
}

// ---------- fused input prep: all fp32->bf16 conversions + bias pack --------
__global__ __launch_bounds__(256) void prep(const float* __restrict__ x,
                                            const float* __restrict__ wq,
                                            const float* __restrict__ wk,
                                            const float* __restrict__ wv,
                                            const float* __restrict__ wo,
                                            const float* __restrict__ mask,
                                            const float* __restrict__ bq,
                                            const float* __restrict__ bk,
                                            const float* __restrict__ bv,
                                            bf16* __restrict__ xb,
                                            bf16* __restrict__ wqkvb,
                                            bf16* __restrict__ wob,
                                            bf16* __restrict__ maskb,
                                            float* __restrict__ bqkv) {
  long i = (long)blockIdx.x * 256 + threadIdx.x;
  if (i < 8650752) {
    const float* src; bf16* dst; long j;
    if (i < 4194304)      { src = x;    dst = xb;              j = i; }
    else if (i < 5242880) { src = wq;   dst = wqkvb;           j = i - 4194304; }
    else if (i < 6291456) { src = wk;   dst = wqkvb + 4194304; j = i - 5242880; }
    else if (i < 7340032) { src = wv;   dst = wqkvb + 8388608; j = i - 6291456; }
    else if (i < 8388608) { src = wo;   dst = wob;             j = i - 7340032; }
    else                  { src = mask; dst = maskb;           j = i - 8388608; }
    float4 v = reinterpret_cast<const float4*>(src)[j];
    bf16x4 o;
    o.x = (bf16)v.x; o.y = (bf16)v.y; o.z = (bf16)v.z; o.w = (bf16)v.w;
    reinterpret_cast<bf16x4*>(dst)[j] = o;
  } else {
    long e = (i - 8650752) * 4;
    const float* s = (e < 2048) ? bq + e : (e < 4096 ? bk + (e - 2048) : bv + (e - 4096));
    *reinterpret_cast<float4*>(bqkv + e) = *reinterpret_cast<const float4*>(s);
  }
}

// =====================================================================
// 256x256 GEMM, round-4 counted-vmcnt schedule: C = A[M,K]*B[N,K]^T,
// 8 waves (2Mx4N), BK=64, 128KiB dbuf LDS, st_16x32 swizzle.
// FUSE=1 (QKV): region n0>>11: 0=Q -> write C (+RoPE); 1=K -> RoPE +
// in-LDS transpose -> Kt[b,h,hd,t]; 2=V -> transpose -> Vt. The K/V
// transpose reuses the (dead) 128KiB LDS in two 64KiB stages with a
// pr^((col&7)<<3) swizzle (8-aligned groups commute with the XOR).
// =====================================================================
#define READ_A4(QA, KS, Ab)                                                   \
  _Pragma("unroll") for (int mi = 0; mi < 4; mi++)                            \
    af[mi] = *reinterpret_cast<const bf16x8*>(                                \
        (Ab) + aoff + ((((QA)*4 + mi)*2) + (KS))*512);

#define READ_B4(KS, Bb)                                                       \
  _Pragma("unroll") for (int ni = 0; ni < 4; ni++)                            \
    bfr[ni] = *reinterpret_cast<const bf16x8*>(                               \
        (Bb) + boff + ((ni*2) + (KS))*512);

#define MFMA16(QA)                                                            \
  _Pragma("unroll") for (int mi = 0; mi < 4; mi++)                            \
  _Pragma("unroll") for (int ni = 0; ni < 4; ni++)                            \
    acc[(QA)*4 + mi][ni] = __builtin_amdgcn_mfma_f32_16x16x32_bf16(           \
        af[mi], bfr[ni], acc[(QA)*4 + mi][ni], 0, 0, 0);

#define STAGE_H0(An, Bn, koff)                                                \
  gl_lds16(agA + (koff),           (An) + wid*1024);                          \
  gl_lds16(agA + 128*la + (koff),  (An) + (wid + 8)*1024);                    \
  gl_lds16(agB + (koff),           (Bn) + wid*1024);                          \
  gl_lds16(agB + 128*lb + (koff),  (Bn) + (wid + 8)*1024);

#define STAGE_H1(An, Bn, koff)                                                \
  gl_lds16(agA + (koff) + 32,          (An) + wid*1024 + 512);                \
  gl_lds16(agA + 128*la + (koff) + 32, (An) + (wid + 8)*1024 + 512);          \
  gl_lds16(agB + (koff) + 32,          (Bn) + wid*1024 + 512);                \
  gl_lds16(agB + 128*lb + (koff) + 32, (Bn) + (wid + 8)*1024 + 512);

// main K-loop body, shared by gemm256 and pv256
#define GEMM256_MAIN_LOOP(NT)                                                 \
  { bf16* An = lds; bf16* Bn = lds + 16384;                                   \
    STAGE_H0(An, Bn, 0); STAGE_H1(An, Bn, 0); }                               \
  for (int t = 0; t < (NT); ++t) {                                            \
    const bf16* Ab = lds + (t & 1) * 32768;                                   \
    const bf16* Bb = Ab + 16384;                                              \
    bf16* An = lds + ((t & 1) ^ 1) * 32768;                                   \
    bf16* Bn = An + 16384;                                                    \
    const long kn = (long)(t + 1) * 64;                                       \
    const bool pf = (t + 1) < (NT);                                           \
    bf16x8 af[4], bfr[4];                                                     \
    asm volatile("s_waitcnt vmcnt(4)" ::: "memory");                          \
    __builtin_amdgcn_s_barrier();                                             \
    READ_A4(0, 0, Ab); READ_B4(0, Bb);                                        \
    if (pf) { STAGE_H0(An, Bn, kn); }                                         \
    asm volatile("s_waitcnt lgkmcnt(0)" ::: "memory");                        \
    __builtin_amdgcn_sched_barrier(0);                                        \
    __builtin_amdgcn_s_setprio(1); MFMA16(0); __builtin_amdgcn_s_setprio(0);  \
    READ_A4(1, 0, Ab);                                                        \
    asm volatile("s_waitcnt lgkmcnt(0)" ::: "memory");                        \
    __builtin_amdgcn_sched_barrier(0);                                        \
    __builtin_amdgcn_s_setprio(1); MFMA16(1); __builtin_amdgcn_s_setprio(0);  \
    if (pf) asm volatile("s_waitcnt vmcnt(4)" ::: "memory");                  \
    else    asm volatile("s_waitcnt vmcnt(0)" ::: "memory");                  \
    __builtin_amdgcn_s_barrier();                                             \
    READ_A4(0, 1, Ab); READ_B4(1, Bb);                                        \
    if (pf) { STAGE_H1(An, Bn, kn); }                                         \
    asm volatile("s_waitcnt lgkmcnt(0)" ::: "memory");                        \
    __builtin_amdgcn_sched_barrier(0);                                        \
    __builtin_amdgcn_s_setprio(1); MFMA16(0); __builtin_amdgcn_s_setprio(0);  \
    READ_A4(1, 1, Ab);                                                        \
    asm volatile("s_waitcnt lgkmcnt(0)" ::: "memory");                        \
    __builtin_amdgcn_sched_barrier(0);                                        \
    __builtin_amdgcn_s_setprio(1); MFMA16(1); __builtin_amdgcn_s_setprio(0);  \
  }

template <typename CT, bool BIAS, bool ACCUM, bool ROPE, int FUSE>
__global__ __launch_bounds__(512, 2) void gemm256(const bf16* __restrict__ A,
                                                  const bf16* __restrict__ Bm,
                                                  const float* __restrict__ bias,
                                                  CT* __restrict__ C,
                                                  int M, int N, int K,
                                                  long la, long lb, long lc,
                                                  long za, long zb, long zc,
                                                  const float* __restrict__ chp,
                                                  const float* __restrict__ shp,
                                                  bf16* __restrict__ Kt,
                                                  bf16* __restrict__ Vt) {
  extern __shared__ __align__(16) bf16 lds[];   // 65536 elems = 128 KiB
  const int z = blockIdx.z;
  A  += (long)z * za;
  Bm += (long)z * zb;
  C  += (long)z * zc;
  const int tid  = threadIdx.x;
  const int wid  = tid >> 6;
  const int lane = tid & 63;
  const int wm0 = (wid >> 2) * 128;
  const int wn0 = (wid & 3) * 64;
  const int m0 = blockIdx.y * 256, n0 = blockIdx.x * 256;

  const int rr = lane >> 2;
  const int cc = ((lane & 3) * 8) ^ ((rr & 8) << 1);
  const bf16* agA = A  + (long)(m0 + wid * 16 + rr) * la + cc;
  const bf16* agB = Bm + (long)(n0 + wid * 16 + rr) * lb + cc;

  const int swz  = ((lane >> 4) * 8) ^ ((lane & 8) << 1);
  const int aoff = (wm0 >> 4) * 1024 + (lane & 15) * 32 + swz;
  const int boff = (wn0 >> 4) * 1024 + (lane & 15) * 32 + swz;

  f32x4 acc[8][4] = {};
  const int NT = K >> 6;

  GEMM256_MAIN_LOOP(NT);

  const bool doRope = ROPE && (((n0 + wn0) & 127) == 0) && ((n0 + wn0) < 4096);

  if (FUSE == 1 && n0 >= 2048) {
    // ---------- K/V region: bias(+RoPE) then in-LDS transpose -> Kt/Vt ----
    const int breg = m0 >> 10;         // batch
    const int t0   = m0 & 1023;        // t base within batch
    const int relc = n0 & 2047;        // region-relative col base
    bf16* XT = (n0 < 4096) ? Kt : Vt;
    __builtin_amdgcn_s_barrier();      // all waves done with main-loop LDS
#pragma unroll
    for (int st = 0; st < 2; ++st) {
#pragma unroll
      for (int mi2 = 0; mi2 < 4; mi2++) {
        const int mi = st * 4 + mi2;
        float vals[4][4];
#pragma unroll
        for (int ni = 0; ni < 4; ni++) {
          const int col = n0 + wn0 + ni * 16 + (lane & 15);
          float bv = 0.0f;
          if constexpr (BIAS) bv = bias[col];
#pragma unroll
          for (int r = 0; r < 4; r++) vals[ni][r] = acc[mi][ni][r] + bv;
        }
        if (doRope) {
#pragma unroll
          for (int ni = 0; ni < 2; ni++)
#pragma unroll
            for (int r = 0; r < 4; r++) {
              const int srow = (m0 + wm0 + mi * 16 + (lane >> 4) * 4 + r) & (S_ - 1);
              const int hd = ni * 16 + (lane & 15);
              const float c  = chp[srow * 32 + hd];
              const float sn = shp[srow * 32 + hd];
              const float a  = vals[ni][r], b2 = vals[ni + 2][r];
              vals[ni][r]     = a * c - b2 * sn;
              vals[ni + 2][r] = b2 * c + a * sn;
            }
        }
#pragma unroll
        for (int ni = 0; ni < 4; ni++) {
          const int col_l = wn0 + ni * 16 + (lane & 15);
          const int row_l = wm0 + mi * 16 + ((lane >> 4) << 2);
          const int pr = (row_l & 63) | ((row_l & 128) >> 1);   // packed row
          bf16x4 o;
          o.x = (bf16)vals[ni][0]; o.y = (bf16)vals[ni][1];
          o.z = (bf16)vals[ni][2]; o.w = (bf16)vals[ni][3];
          *reinterpret_cast<bf16x4*>(
              lds + col_l * 128 + (pr ^ ((col_l & 7) << 3))) = o;
        }
      }
      __builtin_amdgcn_s_barrier();
#pragma unroll
      for (int it = 0; it < 8; ++it) {
        const int idx = it * 512 + tid;
        const int colg = idx >> 4;             // 0..255 (2 heads x 128 hd)
        const int tp8  = (idx & 15) * 8;       // packed-row group
        bf16x8 v = *reinterpret_cast<const bf16x8*>(
            lds + colg * 128 + (tp8 ^ ((colg & 7) << 3)));
        const int trow = (tp8 & 63) + ((tp8 >> 6) << 7) + st * 64;
        const int bh = breg * 16 + (relc >> 7) + (colg >> 7);
        *reinterpret_cast<bf16x8*>(
            XT + (long)bh * (HD_ * S_) + (colg & 127) * S_ + t0 + trow) = v;
      }
      if (st == 0) __builtin_amdgcn_s_barrier();
    }
    return;
  }

  // ---------- normal epilogue (Q region / plain GEMM) ----------
#pragma unroll
  for (int mi = 0; mi < 8; mi++) {
    float vals[4][4];
#pragma unroll
    for (int ni = 0; ni < 4; ni++) {
      const int col = n0 + wn0 + ni * 16 + (lane & 15);
      float bv = 0.0f;
      if constexpr (BIAS) bv = bias[col];
#pragma unroll
      for (int r = 0; r < 4; r++) vals[ni][r] = acc[mi][ni][r] + bv;
    }
    if constexpr (ROPE) {
      if (doRope) {
#pragma unroll
        for (int ni = 0; ni < 2; ni++)
#pragma unroll
          for (int r = 0; r < 4; r++) {
            const int srow = (m0 + wm0 + mi * 16 + (lane >> 4) * 4 + r) & (S_ - 1);
            const int hd = ni * 16 + (lane & 15);
            const float c  = chp[srow * 32 + hd];
            const float sn = shp[srow * 32 + hd];
            const float a  = vals[ni][r], b2 = vals[ni + 2][r];
            vals[ni][r]     = a * c - b2 * sn;
            vals[ni + 2][r] = b2 * c + a * sn;
          }
      }
    }
#pragma unroll
    for (int ni = 0; ni < 4; ni++) {
      const int col = n0 + wn0 + ni * 16 + (lane & 15);
      const long base = (long)(m0 + wm0 + mi * 16 + (lane >> 4) * 4) * lc + col;
#pragma unroll
      for (int r = 0; r < 4; r++) {
        float v = vals[ni][r];
        if constexpr (ACCUM) v += (float)C[base + (long)r * lc];
        C[base + (long)r * lc] = (CT)v;
      }
    }
  }
}

// =====================================================================
// pv256: Ob[b] = mask @ V_b  (K=1024 main loop)  +  Q_b @ W2_b^T (K2=128
// tail fused). Grid (8,4,8): x=col tile, y=row tile, z=b.
// =====================================================================
__global__ __launch_bounds__(512, 2) void pv256(const bf16* __restrict__ Am,
                                                const bf16* __restrict__ Vt,
                                                const bf16* __restrict__ QKV,
                                                const bf16* __restrict__ W2,
                                                bf16* __restrict__ Ob) {
  extern __shared__ __align__(16) bf16 lds[];
  const int z = blockIdx.z;                    // batch b
  const bf16* A  = Am;                         // mask (shared over b)
  const bf16* Bm = Vt + (long)z * (D_ * S_);
  bf16* C = Ob + (long)z * (S_ * D_);
  const long la = S_, lb = S_;
  const int tid  = threadIdx.x;
  const int wid  = tid >> 6;
  const int lane = tid & 63;
  const int wm0 = (wid >> 2) * 128;
  const int wn0 = (wid & 3) * 64;
  const int m0 = blockIdx.y * 256, n0 = blockIdx.x * 256;

  const int rr = lane >> 2;
  const int cc = ((lane & 3) * 8) ^ ((rr & 8) << 1);
  const bf16* agA = A  + (long)(m0 + wid * 16 + rr) * la + cc;
  const bf16* agB = Bm + (long)(n0 + wid * 16 + rr) * lb + cc;

  const int swz  = ((lane >> 4) * 8) ^ ((lane & 8) << 1);
  const int aoff = (wm0 >> 4) * 1024 + (lane & 15) * 32 + swz;
  const int boff = (wn0 >> 4) * 1024 + (lane & 15) * 32 + swz;

  f32x4 acc[8][4] = {};

  GEMM256_MAIN_LOOP(16);

  // ---------------- K2 tail: acc += Q[.,h*128+e] * W2[h][d][e]^T ----------
  const int h0 = n0 >> 7;
  const int hsel = wn0 >> 7;
  const int a2base = hsel * 16384;
  const int b2base = 32768 + hsel * 8192;
  const int bsub = (wn0 & 64) >> 4;
  const int a2off = (wm0 >> 4) * 1024 + (lane & 15) * 32 + swz;
  const int b2off = (lane & 15) * 32 + swz;

#define STAGE_K2(e0)                                                          \
  { const bf16* qa0 = QKV + (long)(z * S_ + m0 + wid * 16 + rr) * NQKV        \
                      + h0 * 128 + (e0) + cc;                                 \
    gl_lds16(qa0,                       lds + wid * 1024);                    \
    gl_lds16(qa0 + 32,                  lds + wid * 1024 + 512);              \
    gl_lds16(qa0 + 128 * NQKV,          lds + (wid + 8) * 1024);              \
    gl_lds16(qa0 + 128 * NQKV + 32,     lds + (wid + 8) * 1024 + 512);        \
    gl_lds16(qa0 + 128,                 lds + 16384 + wid * 1024);            \
    gl_lds16(qa0 + 160,                 lds + 16384 + wid * 1024 + 512);      \
    gl_lds16(qa0 + 128 * NQKV + 128,    lds + 16384 + (wid + 8) * 1024);      \
    gl_lds16(qa0 + 128 * NQKV + 160,    lds + 16384 + (wid + 8) * 1024 + 512);\
    const bf16* w0 = W2 + (long)(z * 16 + h0) * 16384                         \
                     + (wid * 16 + rr) * 128 + (e0) + cc;                     \
    gl_lds16(w0,                        lds + 32768 + wid * 1024);            \
    gl_lds16(w0 + 32,                   lds + 32768 + wid * 1024 + 512);      \
    gl_lds16(w0 + 16384,                lds + 40960 + wid * 1024);            \
    gl_lds16(w0 + 16384 + 32,           lds + 40960 + wid * 1024 + 512);      }

  __builtin_amdgcn_s_barrier();
  STAGE_K2(0);
#pragma unroll
  for (int step = 0; step < 2; step++) {
    asm volatile("s_waitcnt vmcnt(0)" ::: "memory");
    __builtin_amdgcn_s_barrier();
    bf16x8 a2[8], b2[4];
#pragma unroll
    for (int ks = 0; ks < 2; ks++) {
#pragma unroll
      for (int mi = 0; mi < 8; mi++)
        a2[mi] = *reinterpret_cast<const bf16x8*>(
            lds + a2base + a2off + mi * 1024 + ks * 512);
#pragma unroll
      for (int ni = 0; ni < 4; ni++)
        b2[ni] = *reinterpret_cast<const bf16x8*>(
            lds + b2base + b2off + (bsub + ni) * 1024 + ks * 512);
      asm volatile("s_waitcnt lgkmcnt(0)" ::: "memory");
      __builtin_amdgcn_sched_barrier(0);
      __builtin_amdgcn_s_setprio(1);
#pragma unroll
      for (int mi = 0; mi < 8; mi++)
#pragma unroll
        for (int ni = 0; ni < 4; ni++)
          acc[mi][ni] = __builtin_amdgcn_mfma_f32_16x16x32_bf16(
              a2[mi], b2[ni], acc[mi][ni], 0, 0, 0);
      __builtin_amdgcn_s_setprio(0);
    }
    if (step == 0) {
      __builtin_amdgcn_s_barrier();
      STAGE_K2(64);
    }
  }
#undef STAGE_K2

#pragma unroll
  for (int mi = 0; mi < 8; mi++) {
#pragma unroll
    for (int ni = 0; ni < 4; ni++) {
      const int col = n0 + wn0 + ni * 16 + (lane & 15);
      const long base = (long)(m0 + wm0 + mi * 16 + (lane >> 4) * 4) * D_ + col;
#pragma unroll
      for (int r = 0; r < 4; r++)
        C[base + (long)r * D_] = (bf16)acc[mi][ni][r];
    }
  }
}

// ---------- m97-style 128^2 GEMM (kept for small shapes: W2) ----------
template <typename CT, bool BIAS, bool ACCUM>
__global__ __launch_bounds__(256) void gemm_bt(const bf16* __restrict__ A,
                                               const bf16* __restrict__ Bm,
                                               const float* __restrict__ bias,
                                               CT* __restrict__ C,
                                               int M, int N, int K,
                                               long la, long lb, long lc,
                                               long za, long zb, long zc) {
  __shared__ __align__(16) bf16 As[128 * 32];
  __shared__ __align__(16) bf16 Bs[128 * 32];
  const int z = blockIdx.z;
  A  += (long)z * za;
  Bm += (long)z * zb;
  C  += (long)z * zc;
  const int tid = threadIdx.x;
  const int w = tid >> 6, l = tid & 63;
  const int wm = (w & 1) * 64, wn = (w >> 1) * 64;
  const int m0 = blockIdx.y * 128, n0 = blockIdx.x * 128;
  const int lr = l & 15, lk = (l >> 4) * 8;
  const int er = (l >> 4) * 4;

  const bf16* ag = A  + (long)(m0 + (tid >> 2)) * la + (tid & 3) * 8;
  const bf16* bg = Bm + (long)(n0 + (tid >> 2)) * lb + (tid & 3) * 8;
  bf16* al = As + (w * 16) * 32;
  bf16* bl = Bs + (w * 16) * 32;

  f32x4 acc[4][4] = {};

  for (int k0 = 0; k0 < K; k0 += 32) {
    gl_lds16(ag + k0,            al);
    gl_lds16(ag + 64 * la + k0,  al + 64 * 32);
    gl_lds16(bg + k0,            bl);
    gl_lds16(bg + 64 * lb + k0,  bl + 64 * 32);
    __syncthreads();
    bf16x8 afr[4], bfr[4];
#pragma unroll
    for (int mi = 0; mi < 4; mi++)
      afr[mi] = *reinterpret_cast<const bf16x8*>(As + (wm + mi * 16 + lr) * 32 + lk);
#pragma unroll
    for (int ni = 0; ni < 4; ni++)
      bfr[ni] = *reinterpret_cast<const bf16x8*>(Bs + (wn + ni * 16 + lr) * 32 + lk);
#pragma unroll
    for (int mi = 0; mi < 4; mi++)
#pragma unroll
      for (int ni = 0; ni < 4; ni++)
        acc[mi][ni] = __builtin_amdgcn_mfma_f32_16x16x32_bf16(afr[mi], bfr[ni], acc[mi][ni], 0, 0, 0);
    __syncthreads();
  }

#pragma unroll
  for (int mi = 0; mi < 4; mi++) {
#pragma unroll
    for (int ni = 0; ni < 4; ni++) {
      const int col = n0 + wn + ni * 16 + lr;
      float bv = 0.0f;
      if constexpr (BIAS) bv = bias[col];
      const long base = (long)(m0 + wm + mi * 16 + er) * lc + col;
#pragma unroll
      for (int r = 0; r < 4; r++) {
        float v = acc[mi][ni][r] + bv;
        if constexpr (ACCUM) v += (float)C[base + (long)r * lc];
        C[base + (long)r * lc] = (CT)v;
      }
    }
  }
}

extern "C" void kernel_launch(void* const* d_in, const int* in_sizes, int n_in,
                              void* d_out, int out_size, void* d_ws, size_t ws_size,
                              hipStream_t stream) {
  const float* x   = (const float*)d_in[0];
  const float* wq  = (const float*)d_in[1];
  const float* bq  = (const float*)d_in[2];
  const float* wk  = (const float*)d_in[3];
  const float* bk  = (const float*)d_in[4];
  const float* wv  = (const float*)d_in[5];
  const float* bv  = (const float*)d_in[6];
  const float* wo  = (const float*)d_in[7];
  const float* bo  = (const float*)d_in[8];
  const float* ch  = (const float*)d_in[9];
  const float* sh  = (const float*)d_in[10];
  const float* mask = (const float*)d_in[11];
  float* out = (float*)d_out;

  // allow 128 KiB dynamic LDS for the 256^2 kernels
  hipFuncSetAttribute(reinterpret_cast<const void*>(&gemm256<bf16, true, false, true, 1>),
                      hipFuncAttributeMaxDynamicSharedMemorySize, 131072);
  hipFuncSetAttribute(reinterpret_cast<const void*>(&gemm256<float, true, false, false, 0>),
                      hipFuncAttributeMaxDynamicSharedMemorySize, 131072);
  hipFuncSetAttribute(reinterpret_cast<const void*>(&pv256),
                      hipFuncAttributeMaxDynamicSharedMemorySize, 131072);

  char* ws = (char*)d_ws;
  bf16*  QKV   = (bf16*)(ws);                    // 96 MB (only Q region written)
  bf16*  Vt    = (bf16*)(ws + 100663296);        // 32 MB
  bf16*  Kt    = (bf16*)(ws + 134217728);        // 32 MB
  bf16*  wob   = (bf16*)(ws + 167772160);        // 8 MB
  float* bqkv  = (float*)(ws + 176160768);       // 24 KB
  bf16*  maskb = (bf16*)(ws + 176185344);        // 2 MB
  bf16*  W2    = (bf16*)(ws + 178282496);        // 4 MB
  bf16*  Ob    = (bf16*)(ws + 182476800);        // 32 MB
  bf16*  xb    = (bf16*)(ws + 216031232);        // 32 MB (dead after GEMM1)
  bf16*  wqkvb = (bf16*)(ws + 249585664);        // 24 MB (dead after GEMM1)

  // fused conversions + bias pack
  prep<<<33798, 256, 0, stream>>>(x, wq, wk, wv, wo, mask, bq, bk, bv,
                                  xb, wqkvb, wob, maskb, bqkv);

  // QKV projection + RoPE + fused K/V transpose:
  //   Q region -> QKV (roped); K -> Kt (roped, transposed); V -> Vt
  gemm256<bf16, true, false, true, 1><<<dim3(24, 32, 1), 512, 131072, stream>>>(
      xb, wqkvb, bqkv, QKV, NROW, NQKV, D_,
      (long)D_, (long)D_, (long)NQKV, 0L, 0L, 0L, ch, sh, Kt, Vt);

  // W2[bh][d][e] = sum_t V[t,d] K[t,e]   (128 batches of 128x128xK=1024)
  gemm_bt<bf16, false, false><<<dim3(1, 1, 128), 256, 0, stream>>>(
      Vt, Kt, nullptr, W2, HD_, HD_, S_,
      (long)S_, (long)S_, (long)HD_,
      (long)(HD_ * S_), (long)(HD_ * S_), (long)(HD_ * HD_));

  // Ob = mask @ V + Q @ W2^T  (fused; 8 batches of 1024 x 2048)
  pv256<<<dim3(8, 4, 8), 512, 131072, stream>>>(maskb, Vt, QKV, W2, Ob);

  // out = a_sum @ wo^T + bo  (8192 x 2048 x 2048, fp32 output)
  gemm256<float, true, false, false, 0><<<dim3(8, 32, 1), 512, 131072, stream>>>(
      Ob, wob, bo, out, NROW, D_, D_,
      (long)D_, (long)D_, (long)D_, 0L, 0L, 0L, nullptr, nullptr, nullptr, nullptr);
}

// Round 9
// 566.392 us; speedup vs baseline: 1.3761x; 1.0032x over previous
//
#include <hip/hip_runtime.h>
#include <stdint.h>

#define B_ 8
#define S_ 1024
#define D_ 2048
#define H_ 16
#define HD_ 128
#define NROW 8192      // B_*S_
#define NQKV 6144      // 3*D_

typedef __bf16 bf16;
typedef bf16  bf16x8 __attribute__((ext_vector_type(8)));
typedef bf16  bf16x4 __attribute__((ext_vector_type(4)));
typedef float f32x4  __attribute__((ext_vector_type(4)));

#define AS1 __attribute__((address_space(1)))
#define AS3 __attribute__((address_space(3)))

// async global->LDS, 16B per lane; LDS dest = wave-uniform base + lane*16
__device__ __forceinline__ void gl_lds16(const bf16* g, bf16* l) {
  __builtin_amdgcn_global_load_lds((AS1 void*)g, (AS3 void*)l, 16, 0, 0);
}

// ---------- fused input prep: all fp32->bf16 conversions + bias pack --------
__global__ __launch_bounds__(256) void prep(const float* __restrict__ x,
                                            const float* __restrict__ wq,
                                            const float* __restrict__ wk,
                                            const float* __restrict__ wv,
                                            const float* __restrict__ wo,
                                            const float* __restrict__ mask,
                                            const float* __restrict__ bq,
                                            const float* __restrict__ bk,
                                            const float* __restrict__ bv,
                                            bf16* __restrict__ xb,
                                            bf16* __restrict__ wqkvb,
                                            bf16* __restrict__ wob,
                                            bf16* __restrict__ maskb,
                                            float* __restrict__ bqkv) {
  long i = (long)blockIdx.x * 256 + threadIdx.x;
  if (i < 8650752) {
    const float* src; bf16* dst; long j;
    if (i < 4194304)      { src = x;    dst = xb;              j = i; }
    else if (i < 5242880) { src = wq;   dst = wqkvb;           j = i - 4194304; }
    else if (i < 6291456) { src = wk;   dst = wqkvb + 4194304; j = i - 5242880; }
    else if (i < 7340032) { src = wv;   dst = wqkvb + 8388608; j = i - 6291456; }
    else if (i < 8388608) { src = wo;   dst = wob;             j = i - 7340032; }
    else                  { src = mask; dst = maskb;           j = i - 8388608; }
    float4 v = reinterpret_cast<const float4*>(src)[j];
    bf16x4 o;
    o.x = (bf16)v.x; o.y = (bf16)v.y; o.z = (bf16)v.z; o.w = (bf16)v.w;
    reinterpret_cast<bf16x4*>(dst)[j] = o;
  } else {
    long e = (i - 8650752) * 4;
    const float* s = (e < 2048) ? bq + e : (e < 4096 ? bk + (e - 2048) : bv + (e - 4096));
    *reinterpret_cast<float4*>(bqkv + e) = *reinterpret_cast<const float4*>(s);
  }
}

// =====================================================================
// 256x256 GEMM, r4 counted-vmcnt wait/stage structure, UNPINNED phases:
// reads are compiler-visible loads -> read/MFMA/stage fine-grained
// interleave is left to the scheduler (dataflow enforces correctness).
// Required fences only: vmcnt asm (memory clobber: reads can't hoist
// above) + sched_barrier(0) right after each s_barrier (reads can't
// slip between barrier and co-wave drains).
// H0/H1 = kh0/kh1 stage groups (4 gl_lds each per wave).
// P1: vmcnt(4) [H0(t) landed], stage H0(t+1). P3: vmcnt(4) [H1(t)
// landed], stage H1(t+1). 2 barriers/tile; no vmcnt(0) in steady state.
// =====================================================================
#define READ_A4(QA, KS, Ab)                                                   \
  _Pragma("unroll") for (int mi = 0; mi < 4; mi++)                            \
    af[mi] = *reinterpret_cast<const bf16x8*>(                                \
        (Ab) + aoff + ((((QA)*4 + mi)*2) + (KS))*512);

#define READ_B4(KS, Bb)                                                       \
  _Pragma("unroll") for (int ni = 0; ni < 4; ni++)                            \
    bfr[ni] = *reinterpret_cast<const bf16x8*>(                               \
        (Bb) + boff + ((ni*2) + (KS))*512);

#define MFMA16(QA)                                                            \
  _Pragma("unroll") for (int mi = 0; mi < 4; mi++)                            \
  _Pragma("unroll") for (int ni = 0; ni < 4; ni++)                            \
    acc[(QA)*4 + mi][ni] = __builtin_amdgcn_mfma_f32_16x16x32_bf16(           \
        af[mi], bfr[ni], acc[(QA)*4 + mi][ni], 0, 0, 0);

#define STAGE_H0(An, Bn, koff)                                                \
  gl_lds16(agA + (koff),           (An) + wid*1024);                          \
  gl_lds16(agA + 128*la + (koff),  (An) + (wid + 8)*1024);                    \
  gl_lds16(agB + (koff),           (Bn) + wid*1024);                          \
  gl_lds16(agB + 128*lb + (koff),  (Bn) + (wid + 8)*1024);

#define STAGE_H1(An, Bn, koff)                                                \
  gl_lds16(agA + (koff) + 32,          (An) + wid*1024 + 512);                \
  gl_lds16(agA + 128*la + (koff) + 32, (An) + (wid + 8)*1024 + 512);          \
  gl_lds16(agB + (koff) + 32,          (Bn) + wid*1024 + 512);                \
  gl_lds16(agB + 128*lb + (koff) + 32, (Bn) + (wid + 8)*1024 + 512);

// main K-loop body, shared by gemm256 and pv256
#define GEMM256_MAIN_LOOP(NT)                                                 \
  { bf16* An = lds; bf16* Bn = lds + 16384;                                   \
    STAGE_H0(An, Bn, 0); STAGE_H1(An, Bn, 0); }                               \
  for (int t = 0; t < (NT); ++t) {                                            \
    const bf16* Ab = lds + (t & 1) * 32768;                                   \
    const bf16* Bb = Ab + 16384;                                              \
    bf16* An = lds + ((t & 1) ^ 1) * 32768;                                   \
    bf16* Bn = An + 16384;                                                    \
    const long kn = (long)(t + 1) * 64;                                       \
    const bool pf = (t + 1) < (NT);                                           \
    bf16x8 af[4], bfr[4];                                                     \
    asm volatile("s_waitcnt vmcnt(4)" ::: "memory");                          \
    __builtin_amdgcn_s_barrier();                                             \
    __builtin_amdgcn_sched_barrier(0);                                        \
    READ_A4(0, 0, Ab); READ_B4(0, Bb);                                        \
    if (pf) { STAGE_H0(An, Bn, kn); }                                         \
    __builtin_amdgcn_s_setprio(1); MFMA16(0); __builtin_amdgcn_s_setprio(0);  \
    READ_A4(1, 0, Ab);                                                        \
    __builtin_amdgcn_s_setprio(1); MFMA16(1); __builtin_amdgcn_s_setprio(0);  \
    if (pf) asm volatile("s_waitcnt vmcnt(4)" ::: "memory");                  \
    else    asm volatile("s_waitcnt vmcnt(0)" ::: "memory");                  \
    __builtin_amdgcn_s_barrier();                                             \
    __builtin_amdgcn_sched_barrier(0);                                        \
    READ_A4(0, 1, Ab); READ_B4(1, Bb);                                        \
    if (pf) { STAGE_H1(An, Bn, kn); }                                         \
    __builtin_amdgcn_s_setprio(1); MFMA16(0); __builtin_amdgcn_s_setprio(0);  \
    READ_A4(1, 1, Ab);                                                        \
    __builtin_amdgcn_s_setprio(1); MFMA16(1); __builtin_amdgcn_s_setprio(0);  \
  }

template <typename CT, bool BIAS, bool ACCUM, bool ROPE, int FUSE>
__global__ __launch_bounds__(512, 2) void gemm256(const bf16* __restrict__ A,
                                                  const bf16* __restrict__ Bm,
                                                  const float* __restrict__ bias,
                                                  CT* __restrict__ C,
                                                  int M, int N, int K,
                                                  long la, long lb, long lc,
                                                  long za, long zb, long zc,
                                                  const float* __restrict__ chp,
                                                  const float* __restrict__ shp,
                                                  bf16* __restrict__ Kt,
                                                  bf16* __restrict__ Vt) {
  extern __shared__ __align__(16) bf16 lds[];   // 65536 elems = 128 KiB
  const int z = blockIdx.z;
  A  += (long)z * za;
  Bm += (long)z * zb;
  C  += (long)z * zc;
  const int tid  = threadIdx.x;
  const int wid  = tid >> 6;
  const int lane = tid & 63;
  const int wm0 = (wid >> 2) * 128;
  const int wn0 = (wid & 3) * 64;
  const int m0 = blockIdx.y * 256, n0 = blockIdx.x * 256;

  const int rr = lane >> 2;
  const int cc = ((lane & 3) * 8) ^ ((rr & 8) << 1);
  const bf16* agA = A  + (long)(m0 + wid * 16 + rr) * la + cc;
  const bf16* agB = Bm + (long)(n0 + wid * 16 + rr) * lb + cc;

  const int swz  = ((lane >> 4) * 8) ^ ((lane & 8) << 1);
  const int aoff = (wm0 >> 4) * 1024 + (lane & 15) * 32 + swz;
  const int boff = (wn0 >> 4) * 1024 + (lane & 15) * 32 + swz;

  f32x4 acc[8][4] = {};
  const int NT = K >> 6;

  GEMM256_MAIN_LOOP(NT);

  const bool doRope = ROPE && (((n0 + wn0) & 127) == 0) && ((n0 + wn0) < 4096);

  if (FUSE == 1 && n0 >= 2048) {
    // ---------- K/V region: bias(+RoPE) then in-LDS transpose -> Kt/Vt ----
    const int breg = m0 >> 10;         // batch
    const int t0   = m0 & 1023;        // t base within batch
    const int relc = n0 & 2047;        // region-relative col base
    bf16* XT = (n0 < 4096) ? Kt : Vt;
    __builtin_amdgcn_s_barrier();      // all waves done with main-loop LDS
#pragma unroll
    for (int st = 0; st < 2; ++st) {
#pragma unroll
      for (int mi2 = 0; mi2 < 4; mi2++) {
        const int mi = st * 4 + mi2;
        float vals[4][4];
#pragma unroll
        for (int ni = 0; ni < 4; ni++) {
          const int col = n0 + wn0 + ni * 16 + (lane & 15);
          float bv = 0.0f;
          if constexpr (BIAS) bv = bias[col];
#pragma unroll
          for (int r = 0; r < 4; r++) vals[ni][r] = acc[mi][ni][r] + bv;
        }
        if (doRope) {
#pragma unroll
          for (int ni = 0; ni < 2; ni++)
#pragma unroll
            for (int r = 0; r < 4; r++) {
              const int srow = (m0 + wm0 + mi * 16 + (lane >> 4) * 4 + r) & (S_ - 1);
              const int hd = ni * 16 + (lane & 15);
              const float c  = chp[srow * 32 + hd];
              const float sn = shp[srow * 32 + hd];
              const float a  = vals[ni][r], b2 = vals[ni + 2][r];
              vals[ni][r]     = a * c - b2 * sn;
              vals[ni + 2][r] = b2 * c + a * sn;
            }
        }
#pragma unroll
        for (int ni = 0; ni < 4; ni++) {
          const int col_l = wn0 + ni * 16 + (lane & 15);
          const int row_l = wm0 + mi * 16 + ((lane >> 4) << 2);
          const int pr = (row_l & 63) | ((row_l & 128) >> 1);   // packed row
          bf16x4 o;
          o.x = (bf16)vals[ni][0]; o.y = (bf16)vals[ni][1];
          o.z = (bf16)vals[ni][2]; o.w = (bf16)vals[ni][3];
          *reinterpret_cast<bf16x4*>(
              lds + col_l * 128 + (pr ^ ((col_l & 7) << 3))) = o;
        }
      }
      asm volatile("s_waitcnt lgkmcnt(0)" ::: "memory");
      __builtin_amdgcn_s_barrier();
#pragma unroll
      for (int it = 0; it < 8; ++it) {
        const int idx = it * 512 + tid;
        const int colg = idx >> 4;             // 0..255 (2 heads x 128 hd)
        const int tp8  = (idx & 15) * 8;       // packed-row group
        bf16x8 v = *reinterpret_cast<const bf16x8*>(
            lds + colg * 128 + (tp8 ^ ((colg & 7) << 3)));
        const int trow = (tp8 & 63) + ((tp8 >> 6) << 7) + st * 64;
        const int bh = breg * 16 + (relc >> 7) + (colg >> 7);
        *reinterpret_cast<bf16x8*>(
            XT + (long)bh * (HD_ * S_) + (colg & 127) * S_ + t0 + trow) = v;
      }
      if (st == 0) {
        asm volatile("s_waitcnt lgkmcnt(0)" ::: "memory");
        __builtin_amdgcn_s_barrier();
      }
    }
    return;
  }

  // ---------- normal epilogue (Q region / plain GEMM) ----------
#pragma unroll
  for (int mi = 0; mi < 8; mi++) {
    float vals[4][4];
#pragma unroll
    for (int ni = 0; ni < 4; ni++) {
      const int col = n0 + wn0 + ni * 16 + (lane & 15);
      float bv = 0.0f;
      if constexpr (BIAS) bv = bias[col];
#pragma unroll
      for (int r = 0; r < 4; r++) vals[ni][r] = acc[mi][ni][r] + bv;
    }
    if constexpr (ROPE) {
      if (doRope) {
#pragma unroll
        for (int ni = 0; ni < 2; ni++)
#pragma unroll
          for (int r = 0; r < 4; r++) {
            const int srow = (m0 + wm0 + mi * 16 + (lane >> 4) * 4 + r) & (S_ - 1);
            const int hd = ni * 16 + (lane & 15);
            const float c  = chp[srow * 32 + hd];
            const float sn = shp[srow * 32 + hd];
            const float a  = vals[ni][r], b2 = vals[ni + 2][r];
            vals[ni][r]     = a * c - b2 * sn;
            vals[ni + 2][r] = b2 * c + a * sn;
          }
      }
    }
#pragma unroll
    for (int ni = 0; ni < 4; ni++) {
      const int col = n0 + wn0 + ni * 16 + (lane & 15);
      const long base = (long)(m0 + wm0 + mi * 16 + (lane >> 4) * 4) * lc + col;
#pragma unroll
      for (int r = 0; r < 4; r++) {
        float v = vals[ni][r];
        if constexpr (ACCUM) v += (float)C[base + (long)r * lc];
        C[base + (long)r * lc] = (CT)v;
      }
    }
  }
}

// =====================================================================
// pv256: Ob[b] = mask @ V_b  (K=1024 main loop)  +  Q_b @ W2_b^T (K2=128
// tail fused). Grid (8,4,8): x=col tile, y=row tile, z=b.
// =====================================================================
__global__ __launch_bounds__(512, 2) void pv256(const bf16* __restrict__ Am,
                                                const bf16* __restrict__ Vt,
                                                const bf16* __restrict__ QKV,
                                                const bf16* __restrict__ W2,
                                                bf16* __restrict__ Ob) {
  extern __shared__ __align__(16) bf16 lds[];
  const int z = blockIdx.z;                    // batch b
  const bf16* A  = Am;                         // mask (shared over b)
  const bf16* Bm = Vt + (long)z * (D_ * S_);
  bf16* C = Ob + (long)z * (S_ * D_);
  const long la = S_, lb = S_;
  const int tid  = threadIdx.x;
  const int wid  = tid >> 6;
  const int lane = tid & 63;
  const int wm0 = (wid >> 2) * 128;
  const int wn0 = (wid & 3) * 64;
  const int m0 = blockIdx.y * 256, n0 = blockIdx.x * 256;

  const int rr = lane >> 2;
  const int cc = ((lane & 3) * 8) ^ ((rr & 8) << 1);
  const bf16* agA = A  + (long)(m0 + wid * 16 + rr) * la + cc;
  const bf16* agB = Bm + (long)(n0 + wid * 16 + rr) * lb + cc;

  const int swz  = ((lane >> 4) * 8) ^ ((lane & 8) << 1);
  const int aoff = (wm0 >> 4) * 1024 + (lane & 15) * 32 + swz;
  const int boff = (wn0 >> 4) * 1024 + (lane & 15) * 32 + swz;

  f32x4 acc[8][4] = {};

  GEMM256_MAIN_LOOP(16);

  // ---------------- K2 tail: acc += Q[.,h*128+e] * W2[h][d][e]^T ----------
  const int h0 = n0 >> 7;
  const int hsel = wn0 >> 7;
  const int a2base = hsel * 16384;
  const int b2base = 32768 + hsel * 8192;
  const int bsub = (wn0 & 64) >> 4;
  const int a2off = (wm0 >> 4) * 1024 + (lane & 15) * 32 + swz;
  const int b2off = (lane & 15) * 32 + swz;

#define STAGE_K2(e0)                                                          \
  { const bf16* qa0 = QKV + (long)(z * S_ + m0 + wid * 16 + rr) * NQKV        \
                      + h0 * 128 + (e0) + cc;                                 \
    gl_lds16(qa0,                       lds + wid * 1024);                    \
    gl_lds16(qa0 + 32,                  lds + wid * 1024 + 512);              \
    gl_lds16(qa0 + 128 * NQKV,          lds + (wid + 8) * 1024);              \
    gl_lds16(qa0 + 128 * NQKV + 32,     lds + (wid + 8) * 1024 + 512);        \
    gl_lds16(qa0 + 128,                 lds + 16384 + wid * 1024);            \
    gl_lds16(qa0 + 160,                 lds + 16384 + wid * 1024 + 512);      \
    gl_lds16(qa0 + 128 * NQKV + 128,    lds + 16384 + (wid + 8) * 1024);      \
    gl_lds16(qa0 + 128 * NQKV + 160,    lds + 16384 + (wid + 8) * 1024 + 512);\
    const bf16* w0 = W2 + (long)(z * 16 + h0) * 16384                         \
                     + (wid * 16 + rr) * 128 + (e0) + cc;                     \
    gl_lds16(w0,                        lds + 32768 + wid * 1024);            \
    gl_lds16(w0 + 32,                   lds + 32768 + wid * 1024 + 512);      \
    gl_lds16(w0 + 16384,                lds + 40960 + wid * 1024);            \
    gl_lds16(w0 + 16384 + 32,           lds + 40960 + wid * 1024 + 512);      }

  __builtin_amdgcn_s_barrier();
  STAGE_K2(0);
#pragma unroll
  for (int step = 0; step < 2; step++) {
    asm volatile("s_waitcnt vmcnt(0)" ::: "memory");
    __builtin_amdgcn_s_barrier();
    __builtin_amdgcn_sched_barrier(0);
    bf16x8 a2[8], b2[4];
#pragma unroll
    for (int ks = 0; ks < 2; ks++) {
#pragma unroll
      for (int mi = 0; mi < 8; mi++)
        a2[mi] = *reinterpret_cast<const bf16x8*>(
            lds + a2base + a2off + mi * 1024 + ks * 512);
#pragma unroll
      for (int ni = 0; ni < 4; ni++)
        b2[ni] = *reinterpret_cast<const bf16x8*>(
            lds + b2base + b2off + (bsub + ni) * 1024 + ks * 512);
      __builtin_amdgcn_s_setprio(1);
#pragma unroll
      for (int mi = 0; mi < 8; mi++)
#pragma unroll
        for (int ni = 0; ni < 4; ni++)
          acc[mi][ni] = __builtin_amdgcn_mfma_f32_16x16x32_bf16(
              a2[mi], b2[ni], acc[mi][ni], 0, 0, 0);
      __builtin_amdgcn_s_setprio(0);
    }
    if (step == 0) {
      asm volatile("s_waitcnt lgkmcnt(0)" ::: "memory");
      __builtin_amdgcn_s_barrier();
      STAGE_K2(64);
    }
  }
#undef STAGE_K2

#pragma unroll
  for (int mi = 0; mi < 8; mi++) {
#pragma unroll
    for (int ni = 0; ni < 4; ni++) {
      const int col = n0 + wn0 + ni * 16 + (lane & 15);
      const long base = (long)(m0 + wm0 + mi * 16 + (lane >> 4) * 4) * D_ + col;
#pragma unroll
      for (int r = 0; r < 4; r++)
        C[base + (long)r * D_] = (bf16)acc[mi][ni][r];
    }
  }
}

// ---------- m97-style 128^2 GEMM (kept for small shapes: W2) ----------
template <typename CT, bool BIAS, bool ACCUM>
__global__ __launch_bounds__(256) void gemm_bt(const bf16* __restrict__ A,
                                               const bf16* __restrict__ Bm,
                                               const float* __restrict__ bias,
                                               CT* __restrict__ C,
                                               int M, int N, int K,
                                               long la, long lb, long lc,
                                               long za, long zb, long zc) {
  __shared__ __align__(16) bf16 As[128 * 32];
  __shared__ __align__(16) bf16 Bs[128 * 32];
  const int z = blockIdx.z;
  A  += (long)z * za;
  Bm += (long)z * zb;
  C  += (long)z * zc;
  const int tid = threadIdx.x;
  const int w = tid >> 6, l = tid & 63;
  const int wm = (w & 1) * 64, wn = (w >> 1) * 64;
  const int m0 = blockIdx.y * 128, n0 = blockIdx.x * 128;
  const int lr = l & 15, lk = (l >> 4) * 8;
  const int er = (l >> 4) * 4;

  const bf16* ag = A  + (long)(m0 + (tid >> 2)) * la + (tid & 3) * 8;
  const bf16* bg = Bm + (long)(n0 + (tid >> 2)) * lb + (tid & 3) * 8;
  bf16* al = As + (w * 16) * 32;
  bf16* bl = Bs + (w * 16) * 32;

  f32x4 acc[4][4] = {};

  for (int k0 = 0; k0 < K; k0 += 32) {
    gl_lds16(ag + k0,            al);
    gl_lds16(ag + 64 * la + k0,  al + 64 * 32);
    gl_lds16(bg + k0,            bl);
    gl_lds16(bg + 64 * lb + k0,  bl + 64 * 32);
    __syncthreads();
    bf16x8 afr[4], bfr[4];
#pragma unroll
    for (int mi = 0; mi < 4; mi++)
      afr[mi] = *reinterpret_cast<const bf16x8*>(As + (wm + mi * 16 + lr) * 32 + lk);
#pragma unroll
    for (int ni = 0; ni < 4; ni++)
      bfr[ni] = *reinterpret_cast<const bf16x8*>(Bs + (wn + ni * 16 + lr) * 32 + lk);
#pragma unroll
    for (int mi = 0; mi < 4; mi++)
#pragma unroll
      for (int ni = 0; ni < 4; ni++)
        acc[mi][ni] = __builtin_amdgcn_mfma_f32_16x16x32_bf16(afr[mi], bfr[ni], acc[mi][ni], 0, 0, 0);
    __syncthreads();
  }

#pragma unroll
  for (int mi = 0; mi < 4; mi++) {
#pragma unroll
    for (int ni = 0; ni < 4; ni++) {
      const int col = n0 + wn + ni * 16 + lr;
      float bv = 0.0f;
      if constexpr (BIAS) bv = bias[col];
      const long base = (long)(m0 + wm + mi * 16 + er) * lc + col;
#pragma unroll
      for (int r = 0; r < 4; r++) {
        float v = acc[mi][ni][r] + bv;
        if constexpr (ACCUM) v += (float)C[base + (long)r * lc];
        C[base + (long)r * lc] = (CT)v;
      }
    }
  }
}

extern "C" void kernel_launch(void* const* d_in, const int* in_sizes, int n_in,
                              void* d_out, int out_size, void* d_ws, size_t ws_size,
                              hipStream_t stream) {
  const float* x   = (const float*)d_in[0];
  const float* wq  = (const float*)d_in[1];
  const float* bq  = (const float*)d_in[2];
  const float* wk  = (const float*)d_in[3];
  const float* bk  = (const float*)d_in[4];
  const float* wv  = (const float*)d_in[5];
  const float* bv  = (const float*)d_in[6];
  const float* wo  = (const float*)d_in[7];
  const float* bo  = (const float*)d_in[8];
  const float* ch  = (const float*)d_in[9];
  const float* sh  = (const float*)d_in[10];
  const float* mask = (const float*)d_in[11];
  float* out = (float*)d_out;

  // allow 128 KiB dynamic LDS for the 256^2 kernels
  hipFuncSetAttribute(reinterpret_cast<const void*>(&gemm256<bf16, true, false, true, 1>),
                      hipFuncAttributeMaxDynamicSharedMemorySize, 131072);
  hipFuncSetAttribute(reinterpret_cast<const void*>(&gemm256<float, true, false, false, 0>),
                      hipFuncAttributeMaxDynamicSharedMemorySize, 131072);
  hipFuncSetAttribute(reinterpret_cast<const void*>(&pv256),
                      hipFuncAttributeMaxDynamicSharedMemorySize, 131072);

  char* ws = (char*)d_ws;
  bf16*  QKV   = (bf16*)(ws);                    // 96 MB (only Q region written)
  bf16*  Vt    = (bf16*)(ws + 100663296);        // 32 MB
  bf16*  Kt    = (bf16*)(ws + 134217728);        // 32 MB
  bf16*  wob   = (bf16*)(ws + 167772160);        // 8 MB
  float* bqkv  = (float*)(ws + 176160768);       // 24 KB
  bf16*  maskb = (bf16*)(ws + 176185344);        // 2 MB
  bf16*  W2    = (bf16*)(ws + 178282496);        // 4 MB
  bf16*  Ob    = (bf16*)(ws + 182476800);        // 32 MB
  bf16*  xb    = (bf16*)(ws + 216031232);        // 32 MB (dead after GEMM1)
  bf16*  wqkvb = (bf16*)(ws + 249585664);        // 24 MB (dead after GEMM1)

  // fused conversions + bias pack
  prep<<<33798, 256, 0, stream>>>(x, wq, wk, wv, wo, mask, bq, bk, bv,
                                  xb, wqkvb, wob, maskb, bqkv);

  // QKV projection + RoPE + fused K/V transpose:
  //   Q region -> QKV (roped); K -> Kt (roped, transposed); V -> Vt
  gemm256<bf16, true, false, true, 1><<<dim3(24, 32, 1), 512, 131072, stream>>>(
      xb, wqkvb, bqkv, QKV, NROW, NQKV, D_,
      (long)D_, (long)D_, (long)NQKV, 0L, 0L, 0L, ch, sh, Kt, Vt);

  // W2[bh][d][e] = sum_t V[t,d] K[t,e]   (128 batches of 128x128xK=1024)
  gemm_bt<bf16, false, false><<<dim3(1, 1, 128), 256, 0, stream>>>(
      Vt, Kt, nullptr, W2, HD_, HD_, S_,
      (long)S_, (long)S_, (long)HD_,
      (long)(HD_ * S_), (long)(HD_ * S_), (long)(HD_ * HD_));

  // Ob = mask @ V + Q @ W2^T  (fused; 8 batches of 1024 x 2048)
  pv256<<<dim3(8, 4, 8), 512, 131072, stream>>>(maskb, Vt, QKV, W2, Ob);

  // out = a_sum @ wo^T + bo  (8192 x 2048 x 2048, fp32 output)
  gemm256<float, true, false, false, 0><<<dim3(8, 32, 1), 512, 131072, stream>>>(
      Ob, wob, bo, out, NROW, D_, D_,
      (long)D_, (long)D_, (long)D_, 0L, 0L, 0L, nullptr, nullptr, nullptr, nullptr);
}